// Round 18
// baseline (126.368 us; speedup 1.0000x reference)
//
#include <hip/hip_runtime.h>
#include <hip/hip_bf16.h>
#include <math.h>

#define BATCH 8
#define LSEQ 2048
#define DM 128
#define NH 4
#define DK 32
#define REP 5   // PROBE: amplify attnproj key-loop 5x (output invariant: acc and la both scale by REP)

constexpr float SCALE = 0.17677669529663687f;   // 1/sqrt(32)
constexpr float LOG2E = 1.4426950408889634f;
constexpr float SL = SCALE * LOG2E;             // folded into Q at qkv store

typedef __attribute__((ext_vector_type(8))) __bf16 bf16x8;
typedef __attribute__((ext_vector_type(16))) float f32x16;
typedef __attribute__((ext_vector_type(2))) unsigned uint2v;

__device__ __forceinline__ bf16x8 as_bf16x8(uint4 u) {
    union { uint4 a; bf16x8 b; } c; c.a = u; return c.b;
}
__device__ __forceinline__ unsigned pack_bf2(float lo, float hi) {
    __hip_bfloat162 h = __float22bfloat162_rn(make_float2(lo, hi));
    union { __hip_bfloat162 a; unsigned b; } c; c.a = h; return c.b;
}
__device__ __forceinline__ unsigned short bf16u(float f) {
    union { __hip_bfloat16 h; unsigned short u; } c; c.h = __float2bfloat16(f); return c.u;
}

// ---------- kernel 1: QKV projection via MFMA, fused mask-scan, LDS-staged W ----------
__global__ __launch_bounds__(256) void qkv_mfma_kernel(const float* __restrict__ x,
    const float* __restrict__ Wq, const float* __restrict__ Wk, const float* __restrict__ Wv,
    const float* __restrict__ mask,
    unsigned short* __restrict__ Qb, unsigned short* __restrict__ Kb,
    unsigned short* __restrict__ V4, int* __restrict__ cnt,
    int* __restrict__ qpos1, int* __restrict__ qpos0)
{
    const int b = blockIdx.x;                 // 8
    const int which = blockIdx.y;             // 0=Q 1=K 2=V
    const int lt = blockIdx.z;                // 32 tiles of 64 l
    const int tid = threadIdx.x;
    const int wv = tid >> 6;                  // 4 waves
    const int lane = tid & 63;
    const int ql = lane & 31;
    const int hi = lane >> 5;
    const int l = lt * 64 + (wv & 1) * 32 + ql;   // this lane's output row
    const int hbase = (wv >> 1) * 2;              // head pair

    __shared__ unsigned short wl[4][16][32][8];   // 32KB: [h][d/8][dk][d%8]
    __shared__ int slotbuf[64];                   // zeros_before(l) for this tile
    __shared__ int wsumI[4];

    const float* W = (which == 0 ? Wq : (which == 1 ? Wk : Wv));

    // ---- one-time W stage: 16384 floats, coalesced float4, frag-order bf16 ----
    #pragma unroll
    for (int it = 0; it < 16; ++it) {
        const int flat = (it * 256 + tid) * 4;    // float index into W[which]
        float4 v = *reinterpret_cast<const float4*>(W + flat);
        const int dk0 = flat & 31;
        const int d   = (flat >> 5) & 127;
        const int h   = flat >> 12;
        wl[h][d >> 3][dk0 + 0][d & 7] = bf16u(v.x);
        wl[h][d >> 3][dk0 + 1][d & 7] = bf16u(v.y);
        wl[h][d >> 3][dk0 + 2][d & 7] = bf16u(v.z);
        wl[h][d >> 3][dk0 + 3][d & 7] = bf16u(v.w);
    }

    // ---- fused scan of zeros-prefix (all blocks) ----
    {
        const int nchunk = (lt + 1) * 8;          // 8-elem chunks cover [0, (lt+1)*64)
        int c = 0;
        if (tid < nchunk) {
            const float* mb = mask + (size_t)b * LSEQ + tid * 8;
            #pragma unroll
            for (int i = 0; i < 8; ++i) c += (mb[i] == 0.0f) ? 1 : 0;
        }
        int inc = c;                               // wave-inclusive scan (64 lanes)
        #pragma unroll
        for (int off = 1; off < 64; off <<= 1) {
            int v = __shfl_up(inc, off);
            if (lane >= off) inc += v;
        }
        if (lane == 63) wsumI[wv] = inc;
        __syncthreads();
        int wpre = 0;
        #pragma unroll
        for (int wN = 0; wN < 4; ++wN) if (wN < wv) wpre += wsumI[wN];
        const int excl = wpre + inc - c;           // exclusive prefix of chunk tid
        if (tid >= lt * 8 && tid < lt * 8 + 8) {   // chunks covering this block's 64 l's
            const float* mb = mask + (size_t)b * LSEQ + tid * 8;
            int run = excl;
            #pragma unroll
            for (int i = 0; i < 8; ++i) {
                slotbuf[(tid - lt * 8) * 8 + i] = run;
                run += (mb[i] == 0.0f) ? 1 : 0;
            }
        }
        if (which == 1 && lt == 31 && tid == 255) cnt[b] = wpre + inc;  // total zeros
    }
    __syncthreads();                               // covers W stage + scan

    // ---- position maps (which==1 blocks only; one write per l) ----
    if (which == 1 && tid < 64) {
        const int l64 = lt * 64 + tid;
        const int s = slotbuf[tid];                // zeros before l64
        if (mask[(size_t)b * LSEQ + l64] == 0.0f) qpos0[b * LSEQ + s] = l64;        // zero-output query
        else                                      qpos1[b * LSEQ + (l64 - s)] = l64; // active query
    }

    const float* xcol = x + (size_t)b * DM * LSEQ + l;   // x[b][d][l]

    f32x16 acc0, acc1;
    #pragma unroll
    for (int r = 0; r < 16; ++r) { acc0[r] = 0.f; acc1[r] = 0.f; }

    #pragma unroll
    for (int d0 = 0; d0 < DM; d0 += 16) {
        const int dblk = (d0 >> 3) + hi;
        float xv[8];
        #pragma unroll
        for (int i = 0; i < 8; ++i) xv[i] = xcol[(size_t)(d0 + 8 * hi + i) * LSEQ];
        uint4 xp = make_uint4(pack_bf2(xv[0], xv[1]), pack_bf2(xv[2], xv[3]),
                              pack_bf2(xv[4], xv[5]), pack_bf2(xv[6], xv[7]));
        const bf16x8 xf = as_bf16x8(xp);
        uint4 wp0 = *reinterpret_cast<const uint4*>(&wl[hbase + 0][dblk][ql][0]);
        uint4 wp1 = *reinterpret_cast<const uint4*>(&wl[hbase + 1][dblk][ql][0]);
        acc0 = __builtin_amdgcn_mfma_f32_32x32x16_bf16(as_bf16x8(wp0), xf, acc0, 0, 0, 0);
        acc1 = __builtin_amdgcn_mfma_f32_32x32x16_bf16(as_bf16x8(wp1), xf, acc1, 0, 0, 0);
    }

    // Q compacts by mask==1 (active queries); K/V compact by mask==0 (live keys)
    const float mv = mask[(size_t)b * LSEQ + l];
    const int zb = slotbuf[(wv & 1) * 32 + ql];    // zeros before l
    bool store;
    int slot;
    if (which == 0) { store = (mv != 0.0f); slot = l - zb; }
    else            { store = (mv == 0.0f); slot = zb; }
    if (store) {
        if (which < 2) {
            const float fold = (which == 0) ? SL : 1.0f;
            unsigned short* base0 = (which == 0 ? Qb : Kb);
            #pragma unroll
            for (int hh = 0; hh < 2; ++hh) {
                const f32x16& A = hh ? acc1 : acc0;
                const int bh = b * NH + hbase + hh;
                unsigned short* rowp = base0 + ((size_t)bh * LSEQ + slot) * DK;
                unsigned dw[8];
                #pragma unroll
                for (int j = 0; j < 8; ++j) dw[j] = pack_bf2(A[2*j] * fold, A[2*j+1] * fold);
                *reinterpret_cast<uint2*>(rowp + 4*hi)      = make_uint2(dw[0], dw[1]);
                *reinterpret_cast<uint2*>(rowp + 8 + 4*hi)  = make_uint2(dw[2], dw[3]);
                *reinterpret_cast<uint2*>(rowp + 16 + 4*hi) = make_uint2(dw[4], dw[5]);
                *reinterpret_cast<uint2*>(rowp + 24 + 4*hi) = make_uint2(dw[6], dw[7]);
            }
        } else {
            const int sbase = (slot >> 5) * 1024 + ((slot >> 4) & 1) * 512
                            + ((slot >> 3) & 1) * 256 + (slot & 7) + hi * 32;
            #pragma unroll
            for (int hh = 0; hh < 2; ++hh) {
                const f32x16& A = hh ? acc1 : acc0;
                const int bh = b * NH + hbase + hh;
                unsigned short* vb = V4 + (size_t)bh * (LSEQ * DK) + sbase;
                #pragma unroll
                for (int r = 0; r < 16; ++r)
                    vb[8 * (r & 3) + 64 * (r >> 2)] = bf16u(A[r]);
            }
        }
    }
}

// ---------- kernel 2: fused MFMA flash attention + output projection ----------
// PROBE BUILD: key loop repeated REP times; acc and la both scale by REP so the
// normalized output is invariant. Purpose: lift attnproj above the ~41us poison
// fills so rocprof's top-5 finally shows its counters.
__global__ __launch_bounds__(512, 4) void attnproj_kernel(
    const unsigned short* __restrict__ Qb, const unsigned short* __restrict__ Kb,
    const unsigned short* __restrict__ V4,
    const int* __restrict__ cnt, const int* __restrict__ qpos1,
    const int* __restrict__ qpos0, const float* __restrict__ Wo,
    float* __restrict__ out)
{
    const int b = blockIdx.x & 7;                 // XCD-pinned batch
    const int q0 = (blockIdx.x >> 3) * 32;
    const int tid = threadIdx.x;
    const int wid = tid >> 6;                     // 8 waves
    const int h = wid >> 1;                       // head
    const int kw = wid & 1;                       // key-half owner
    const int lane = tid & 63;
    const int ql = lane & 31;
    const int hi = lane >> 5;
    const int bh = b * NH + h;
    const int n = cnt[b];                         // live keys (mask==0)
    const int nq = LSEQ - n;                      // active queries (mask==1)

    if (q0 >= nq) {                               // pure zero-output block
        if (wid < 4) {
            const int jq = wid;
            const int pos = qpos0[b * LSEQ + (q0 + ql - nq)];
            float* obase = out + (size_t)b * DM * LSEQ + pos;
            #pragma unroll
            for (int r = 0; r < 16; ++r) {
                const int j = jq * 32 + (r & 3) + 8 * (r >> 2) + 4 * hi;
                obase[(size_t)j * LSEQ] = 0.f;
            }
        }
        return;
    }

    __shared__ __align__(16) char smem[17408];
    float* red = reinterpret_cast<float*>(smem);                  // [4][64][17]
    unsigned short* hd = reinterpret_cast<unsigned short*>(smem); // [32][136]

    const uint4* Qp = reinterpret_cast<const uint4*>(Qb + ((size_t)bh * LSEQ + q0 + ql) * DK);
    const bf16x8 qf0 = as_bf16x8(Qp[hi]);         // compacted Q (pre-scaled)
    const bf16x8 qf1 = as_bf16x8(Qp[2 + hi]);

    const unsigned short* Kbase = Kb + (size_t)bh * LSEQ * DK;
    const unsigned short* Vb4   = V4 + (size_t)bh * LSEQ * DK;

    f32x16 acc;
    #pragma unroll
    for (int r = 0; r < 16; ++r) acc[r] = 0.f;
    f32x16 zero;
    #pragma unroll
    for (int r = 0; r < 16; ++r) zero[r] = 0.f;
    float la0 = 0.f, la1 = 0.f;

    auto ldk0 = [&](int k) { return reinterpret_cast<const uint4*>(Kbase + (size_t)(k + ql) * DK)[hi]; };
    auto ldk1 = [&](int k) { return reinterpret_cast<const uint4*>(Kbase + (size_t)(k + ql) * DK)[2 + hi]; };
    auto ldv0 = [&](int k) { return reinterpret_cast<const uint4*>(Vb4 + (size_t)(k >> 5) * 1024)[lane]; };
    auto ldv1 = [&](int k) { return reinterpret_cast<const uint4*>(Vb4 + (size_t)(k >> 5) * 1024)[64 + lane]; };

    auto compute = [&](uint4 kv0, uint4 kv1, uint4 vv0, uint4 vv1, int k0, bool pred) {
        f32x16 s = __builtin_amdgcn_mfma_f32_32x32x16_bf16(as_bf16x8(kv0), qf0, zero, 0, 0, 0);
        s = __builtin_amdgcn_mfma_f32_32x32x16_bf16(as_bf16x8(kv1), qf1, s, 0, 0, 0);
        unsigned w[8];
        #pragma unroll
        for (int j = 0; j < 8; ++j) {
            float e0 = exp2f(s[2*j]);             // key = k0+(r&3)+8*(r>>2)+4*hi
            float e1 = exp2f(s[2*j+1]);
            if (pred) {
                const int r0 = 2*j, r1 = 2*j + 1;
                if (k0 + (r0 & 3) + 8*(r0 >> 2) + 4*hi >= n) e0 = 0.f;
                if (k0 + (r1 & 3) + 8*(r1 >> 2) + 4*hi >= n) e1 = 0.f;
            }
            la0 += e0;
            la1 += e1;
            w[j] = pack_bf2(e0, e1);
        }
        uint2v p0 = __builtin_amdgcn_permlane32_swap(w[0], w[2], false, false);
        uint2v p1 = __builtin_amdgcn_permlane32_swap(w[1], w[3], false, false);
        uint2v p2 = __builtin_amdgcn_permlane32_swap(w[4], w[6], false, false);
        uint2v p3 = __builtin_amdgcn_permlane32_swap(w[5], w[7], false, false);
        uint4 b0 = make_uint4(p0[0], p1[0], p0[1], p1[1]);
        uint4 b1 = make_uint4(p2[0], p3[0], p2[1], p3[1]);
        acc = __builtin_amdgcn_mfma_f32_32x32x16_bf16(as_bf16x8(vv0), as_bf16x8(b0), acc, 0, 0, 0);
        acc = __builtin_amdgcn_mfma_f32_32x32x16_bf16(as_bf16x8(vv1), as_bf16x8(b1), acc, 0, 0, 0);
    };

    for (int rep = 0; rep < REP; ++rep) {         // PROBE amplification
        const int nfull = n & ~31;
        int k = kw * 32;
        if (k < nfull) {
            uint4 ka0 = ldk0(k), ka1 = ldk1(k), va0 = ldv0(k), va1 = ldv1(k);
            for (; k + 64 < nfull; k += 64) {
                uint4 kb0 = ldk0(k + 64), kb1 = ldk1(k + 64);
                uint4 vb0 = ldv0(k + 64), vb1 = ldv1(k + 64);
                compute(ka0, ka1, va0, va1, k, false);
                ka0 = kb0; ka1 = kb1; va0 = vb0; va1 = vb1;
            }
            compute(ka0, ka1, va0, va1, k, false);
        }
        if ((n & 31) && (((nfull >> 5) & 1) == kw)) {
            uint4 ka0 = ldk0(nfull), ka1 = ldk1(nfull);
            uint4 va0 = ldv0(nfull), va1 = ldv1(nfull);
            compute(ka0, ka1, va0, va1, nfull, true);
        }
    }

    float la = la0 + la1;

    // ---- merge the two key-half partials (one LDS round) ----
    if (kw == 1) {
        float* r0 = red + ((size_t)h * 64 + lane) * 17;
        #pragma unroll
        for (int r = 0; r < 16; ++r) r0[r] = acc[r];
        r0[16] = la;
    }
    __syncthreads();
    float wgt = 0.f;
    if (kw == 0) {
        const float* r0 = red + ((size_t)h * 64 + lane) * 17;
        #pragma unroll
        for (int r = 0; r < 16; ++r) acc[r] += r0[r];
        la += r0[16];
        const float lf = la + __shfl_xor(la, 32);
        wgt = (lf > 0.f) ? (1.0f / lf) : 0.f;     // REP scaling cancels in acc/lf
    }
    __syncthreads();                              // red dead; reuse as hd

    // ---- stage normalized O-tile (32 q x 128 d) in LDS as bf16 ----
    if (kw == 0) {
        unsigned short* hrow = hd + ql * 136 + h * DK + 4 * hi;
        #pragma unroll
        for (int g = 0; g < 4; ++g) {             // d = 8g + 4hi + (0..3)
            uint2 p = make_uint2(pack_bf2(acc[4*g+0]*wgt, acc[4*g+1]*wgt),
                                 pack_bf2(acc[4*g+2]*wgt, acc[4*g+3]*wgt));
            *reinterpret_cast<uint2*>(hrow + 8*g) = p;
        }
    }
    __syncthreads();

    // ---- output projection: waves 0-3, one j-quarter each; scattered cols ----
    if (wid < 4) {
        const int jq = wid;
        f32x16 pacc;
        #pragma unroll
        for (int r = 0; r < 16; ++r) pacc[r] = 0.f;
        #pragma unroll
        for (int ks = 0; ks < 8; ++ks) {
            const int k0 = ks * 16 + 8 * hi;
            uint4 bp = *reinterpret_cast<const uint4*>(hd + ql * 136 + k0);
            const float* wcol = Wo + (size_t)k0 * DM + jq * 32 + ql;
            float w[8];
            #pragma unroll
            for (int i = 0; i < 8; ++i) w[i] = wcol[(size_t)i * DM];
            uint4 ap = make_uint4(pack_bf2(w[0], w[1]), pack_bf2(w[2], w[3]),
                                  pack_bf2(w[4], w[5]), pack_bf2(w[6], w[7]));
            pacc = __builtin_amdgcn_mfma_f32_32x32x16_bf16(as_bf16x8(ap), as_bf16x8(bp), pacc, 0, 0, 0);
        }
        const int i = q0 + ql;
        const bool valid = (i < nq);              // mixed-tile tail lanes -> zeros
        const int pos = valid ? qpos1[b * LSEQ + i] : qpos0[b * LSEQ + (i - nq)];
        float* obase = out + (size_t)b * DM * LSEQ + pos;
        #pragma unroll
        for (int r = 0; r < 16; ++r) {
            const int j = jq * 32 + (r & 3) + 8 * (r >> 2) + 4 * hi;
            obase[(size_t)j * LSEQ] = valid ? pacc[r] : 0.f;
        }
    }
}

extern "C" void kernel_launch(void* const* d_in, const int* in_sizes, int n_in,
                              void* d_out, int out_size, void* d_ws, size_t ws_size,
                              hipStream_t stream)
{
    const float* x    = (const float*)d_in[0];
    const float* mask = (const float*)d_in[1];
    const float* Wq   = (const float*)d_in[2];
    const float* Wk   = (const float*)d_in[3];
    const float* Wv   = (const float*)d_in[4];
    const float* Wo   = (const float*)d_in[5];
    float* out = (float*)d_out;

    char* wsb = (char*)d_ws;
    const size_t NBF = (size_t)BATCH * NH * LSEQ * DK;      // 2,097,152 elems
    unsigned short* Qb  = (unsigned short*)wsb;             // 4MB
    unsigned short* Kb  = Qb + NBF;                         // 4MB
    unsigned short* V4  = Kb + NBF;                         // 4MB frag-layout V
    int* cnt   = (int*)(wsb + 24ull * 1024 * 1024);         // 32B
    int* qpos1 = (int*)(wsb + 24ull * 1024 * 1024 + 4096);  // 64KB (active queries)
    int* qpos0 = qpos1 + (size_t)BATCH * LSEQ;              // 64KB (zeroed queries)

    qkv_mfma_kernel<<<dim3(BATCH, 3, LSEQ / 64), dim3(256), 0, stream>>>(
        x, Wq, Wk, Wv, mask, Qb, Kb, V4, cnt, qpos1, qpos0);
    attnproj_kernel<<<dim3(BATCH * LSEQ / 32), dim3(512), 0, stream>>>(
        Qb, Kb, V4, cnt, qpos1, qpos0, Wo, out);
}

// Round 19
// 47.000 us; speedup vs baseline: 2.6887x; 2.6887x over previous
//
#include <hip/hip_runtime.h>
#include <hip/hip_bf16.h>
#include <math.h>

#define BATCH 8
#define LSEQ 2048
#define DM 128
#define NH 4
#define DK 32

constexpr float SCALE = 0.17677669529663687f;   // 1/sqrt(32)
constexpr float LOG2E = 1.4426950408889634f;
constexpr float SL = SCALE * LOG2E;             // folded into Q at qkv store

typedef __attribute__((ext_vector_type(8))) __bf16 bf16x8;
typedef __attribute__((ext_vector_type(16))) float f32x16;
typedef __attribute__((ext_vector_type(2))) unsigned uint2v;

__device__ __forceinline__ bf16x8 as_bf16x8(uint4 u) {
    union { uint4 a; bf16x8 b; } c; c.a = u; return c.b;
}
__device__ __forceinline__ unsigned pack_bf2(float lo, float hi) {
    __hip_bfloat162 h = __float22bfloat162_rn(make_float2(lo, hi));
    union { __hip_bfloat162 a; unsigned b; } c; c.a = h; return c.b;
}
__device__ __forceinline__ unsigned short bf16u(float f) {
    union { __hip_bfloat16 h; unsigned short u; } c; c.h = __float2bfloat16(f); return c.u;
}

// ---------- kernel 1: QKV projection via MFMA, fused mask-scan, LDS-staged W ----------
__global__ __launch_bounds__(256) void qkv_mfma_kernel(const float* __restrict__ x,
    const float* __restrict__ Wq, const float* __restrict__ Wk, const float* __restrict__ Wv,
    const float* __restrict__ mask,
    unsigned short* __restrict__ Qb, unsigned short* __restrict__ Kb,
    unsigned short* __restrict__ V4, int* __restrict__ cnt,
    int* __restrict__ qpos1, int* __restrict__ qpos0)
{
    const int b = blockIdx.x;                 // 8
    const int which = blockIdx.y;             // 0=Q 1=K 2=V
    const int lt = blockIdx.z;                // 32 tiles of 64 l
    const int tid = threadIdx.x;
    const int wv = tid >> 6;                  // 4 waves
    const int lane = tid & 63;
    const int ql = lane & 31;
    const int hi = lane >> 5;
    const int l = lt * 64 + (wv & 1) * 32 + ql;   // this lane's output row
    const int hbase = (wv >> 1) * 2;              // head pair

    __shared__ unsigned short wl[4][16][32][8];   // 32KB: [h][d/8][dk][d%8]
    __shared__ int slotbuf[64];                   // zeros_before(l) for this tile
    __shared__ int wsumI[4];

    const float* W = (which == 0 ? Wq : (which == 1 ? Wk : Wv));

    // ---- one-time W stage: 16384 floats, coalesced float4, frag-order bf16 ----
    #pragma unroll
    for (int it = 0; it < 16; ++it) {
        const int flat = (it * 256 + tid) * 4;    // float index into W[which]
        float4 v = *reinterpret_cast<const float4*>(W + flat);
        const int dk0 = flat & 31;
        const int d   = (flat >> 5) & 127;
        const int h   = flat >> 12;
        wl[h][d >> 3][dk0 + 0][d & 7] = bf16u(v.x);
        wl[h][d >> 3][dk0 + 1][d & 7] = bf16u(v.y);
        wl[h][d >> 3][dk0 + 2][d & 7] = bf16u(v.z);
        wl[h][d >> 3][dk0 + 3][d & 7] = bf16u(v.w);
    }

    // ---- fused scan of zeros-prefix (all blocks) ----
    {
        const int nchunk = (lt + 1) * 8;          // 8-elem chunks cover [0, (lt+1)*64)
        int c = 0;
        if (tid < nchunk) {
            const float* mb = mask + (size_t)b * LSEQ + tid * 8;
            #pragma unroll
            for (int i = 0; i < 8; ++i) c += (mb[i] == 0.0f) ? 1 : 0;
        }
        int inc = c;                               // wave-inclusive scan (64 lanes)
        #pragma unroll
        for (int off = 1; off < 64; off <<= 1) {
            int v = __shfl_up(inc, off);
            if (lane >= off) inc += v;
        }
        if (lane == 63) wsumI[wv] = inc;
        __syncthreads();
        int wpre = 0;
        #pragma unroll
        for (int wN = 0; wN < 4; ++wN) if (wN < wv) wpre += wsumI[wN];
        const int excl = wpre + inc - c;           // exclusive prefix of chunk tid
        if (tid >= lt * 8 && tid < lt * 8 + 8) {   // chunks covering this block's 64 l's
            const float* mb = mask + (size_t)b * LSEQ + tid * 8;
            int run = excl;
            #pragma unroll
            for (int i = 0; i < 8; ++i) {
                slotbuf[(tid - lt * 8) * 8 + i] = run;
                run += (mb[i] == 0.0f) ? 1 : 0;
            }
        }
        if (which == 1 && lt == 31 && tid == 255) cnt[b] = wpre + inc;  // total zeros
    }
    __syncthreads();                               // covers W stage + scan

    // ---- position maps (which==1 blocks only; one write per l) ----
    if (which == 1 && tid < 64) {
        const int l64 = lt * 64 + tid;
        const int s = slotbuf[tid];                // zeros before l64
        if (mask[(size_t)b * LSEQ + l64] == 0.0f) qpos0[b * LSEQ + s] = l64;        // zero-output query
        else                                      qpos1[b * LSEQ + (l64 - s)] = l64; // active query
    }

    const float* xcol = x + (size_t)b * DM * LSEQ + l;   // x[b][d][l]

    f32x16 acc0, acc1;
    #pragma unroll
    for (int r = 0; r < 16; ++r) { acc0[r] = 0.f; acc1[r] = 0.f; }

    #pragma unroll
    for (int d0 = 0; d0 < DM; d0 += 16) {
        const int dblk = (d0 >> 3) + hi;
        float xv[8];
        #pragma unroll
        for (int i = 0; i < 8; ++i) xv[i] = xcol[(size_t)(d0 + 8 * hi + i) * LSEQ];
        uint4 xp = make_uint4(pack_bf2(xv[0], xv[1]), pack_bf2(xv[2], xv[3]),
                              pack_bf2(xv[4], xv[5]), pack_bf2(xv[6], xv[7]));
        const bf16x8 xf = as_bf16x8(xp);
        uint4 wp0 = *reinterpret_cast<const uint4*>(&wl[hbase + 0][dblk][ql][0]);
        uint4 wp1 = *reinterpret_cast<const uint4*>(&wl[hbase + 1][dblk][ql][0]);
        acc0 = __builtin_amdgcn_mfma_f32_32x32x16_bf16(as_bf16x8(wp0), xf, acc0, 0, 0, 0);
        acc1 = __builtin_amdgcn_mfma_f32_32x32x16_bf16(as_bf16x8(wp1), xf, acc1, 0, 0, 0);
    }

    // Q compacts by mask==1 (active queries); K/V compact by mask==0 (live keys)
    const float mv = mask[(size_t)b * LSEQ + l];
    const int zb = slotbuf[(wv & 1) * 32 + ql];    // zeros before l
    bool store;
    int slot;
    if (which == 0) { store = (mv != 0.0f); slot = l - zb; }
    else            { store = (mv == 0.0f); slot = zb; }
    if (store) {
        if (which < 2) {
            const float fold = (which == 0) ? SL : 1.0f;
            unsigned short* base0 = (which == 0 ? Qb : Kb);
            #pragma unroll
            for (int hh = 0; hh < 2; ++hh) {
                const f32x16& A = hh ? acc1 : acc0;
                const int bh = b * NH + hbase + hh;
                unsigned short* rowp = base0 + ((size_t)bh * LSEQ + slot) * DK;
                unsigned dw[8];
                #pragma unroll
                for (int j = 0; j < 8; ++j) dw[j] = pack_bf2(A[2*j] * fold, A[2*j+1] * fold);
                *reinterpret_cast<uint2*>(rowp + 4*hi)      = make_uint2(dw[0], dw[1]);
                *reinterpret_cast<uint2*>(rowp + 8 + 4*hi)  = make_uint2(dw[2], dw[3]);
                *reinterpret_cast<uint2*>(rowp + 16 + 4*hi) = make_uint2(dw[4], dw[5]);
                *reinterpret_cast<uint2*>(rowp + 24 + 4*hi) = make_uint2(dw[6], dw[7]);
            }
        } else {
            const int sbase = (slot >> 5) * 1024 + ((slot >> 4) & 1) * 512
                            + ((slot >> 3) & 1) * 256 + (slot & 7) + hi * 32;
            #pragma unroll
            for (int hh = 0; hh < 2; ++hh) {
                const f32x16& A = hh ? acc1 : acc0;
                const int bh = b * NH + hbase + hh;
                unsigned short* vb = V4 + (size_t)bh * (LSEQ * DK) + sbase;
                #pragma unroll
                for (int r = 0; r < 16; ++r)
                    vb[8 * (r & 3) + 64 * (r >> 2)] = bf16u(A[r]);
            }
        }
    }
}

// ---------- kernel 2: fused MFMA flash attention + output projection ----------
// 1024 threads = 16 waves = (4 heads x 4-way key split) -> 4 waves/SIMD during
// the heavy phase (was 2; probe R18 showed occupancy 14%, VALUBusy 42%).
// Merge: one LDS round, 3 partials per head. Proj runs on the kw==0 waves.
__global__ __launch_bounds__(1024, 4) void attnproj_kernel(
    const unsigned short* __restrict__ Qb, const unsigned short* __restrict__ Kb,
    const unsigned short* __restrict__ V4,
    const int* __restrict__ cnt, const int* __restrict__ qpos1,
    const int* __restrict__ qpos0, const float* __restrict__ Wo,
    float* __restrict__ out)
{
    const int b = blockIdx.x & 7;                 // XCD-pinned batch
    const int q0 = (blockIdx.x >> 3) * 32;
    const int tid = threadIdx.x;
    const int wid = tid >> 6;                     // 16 waves
    const int h = wid >> 2;                       // head
    const int kw = wid & 3;                       // key-quarter owner
    const int lane = tid & 63;
    const int ql = lane & 31;
    const int hi = lane >> 5;
    const int bh = b * NH + h;
    const int n = cnt[b];                         // live keys (mask==0)
    const int nq = LSEQ - n;                      // active queries (mask==1)

    if (q0 >= nq) {                               // pure zero-output block
        if (kw == 0) {
            const int jq = h;
            const int pos = qpos0[b * LSEQ + (q0 + ql - nq)];
            float* obase = out + (size_t)b * DM * LSEQ + pos;
            #pragma unroll
            for (int r = 0; r < 16; ++r) {
                const int j = jq * 32 + (r & 3) + 8 * (r >> 2) + 4 * hi;
                obase[(size_t)j * LSEQ] = 0.f;
            }
        }
        return;
    }

    __shared__ __align__(16) char smem[52224];    // red[4][3][64][17] f32; hd overlaid
    float* red = reinterpret_cast<float*>(smem);
    unsigned short* hd = reinterpret_cast<unsigned short*>(smem); // [32][136]

    const uint4* Qp = reinterpret_cast<const uint4*>(Qb + ((size_t)bh * LSEQ + q0 + ql) * DK);
    const bf16x8 qf0 = as_bf16x8(Qp[hi]);         // compacted Q (pre-scaled)
    const bf16x8 qf1 = as_bf16x8(Qp[2 + hi]);

    const unsigned short* Kbase = Kb + (size_t)bh * LSEQ * DK;
    const unsigned short* Vb4   = V4 + (size_t)bh * LSEQ * DK;

    f32x16 acc;
    #pragma unroll
    for (int r = 0; r < 16; ++r) acc[r] = 0.f;
    f32x16 zero;
    #pragma unroll
    for (int r = 0; r < 16; ++r) zero[r] = 0.f;
    float la0 = 0.f, la1 = 0.f;

    auto ldk0 = [&](int k) { return reinterpret_cast<const uint4*>(Kbase + (size_t)(k + ql) * DK)[hi]; };
    auto ldk1 = [&](int k) { return reinterpret_cast<const uint4*>(Kbase + (size_t)(k + ql) * DK)[2 + hi]; };
    auto ldv0 = [&](int k) { return reinterpret_cast<const uint4*>(Vb4 + (size_t)(k >> 5) * 1024)[lane]; };
    auto ldv1 = [&](int k) { return reinterpret_cast<const uint4*>(Vb4 + (size_t)(k >> 5) * 1024)[64 + lane]; };

    auto compute = [&](uint4 kv0, uint4 kv1, uint4 vv0, uint4 vv1, int k0, bool pred) {
        f32x16 s = __builtin_amdgcn_mfma_f32_32x32x16_bf16(as_bf16x8(kv0), qf0, zero, 0, 0, 0);
        s = __builtin_amdgcn_mfma_f32_32x32x16_bf16(as_bf16x8(kv1), qf1, s, 0, 0, 0);
        unsigned w[8];
        #pragma unroll
        for (int j = 0; j < 8; ++j) {
            float e0 = exp2f(s[2*j]);             // key = k0+(r&3)+8*(r>>2)+4*hi
            float e1 = exp2f(s[2*j+1]);
            if (pred) {
                const int r0 = 2*j, r1 = 2*j + 1;
                if (k0 + (r0 & 3) + 8*(r0 >> 2) + 4*hi >= n) e0 = 0.f;
                if (k0 + (r1 & 3) + 8*(r1 >> 2) + 4*hi >= n) e1 = 0.f;
            }
            la0 += e0;
            la1 += e1;
            w[j] = pack_bf2(e0, e1);
        }
        uint2v p0 = __builtin_amdgcn_permlane32_swap(w[0], w[2], false, false);
        uint2v p1 = __builtin_amdgcn_permlane32_swap(w[1], w[3], false, false);
        uint2v p2 = __builtin_amdgcn_permlane32_swap(w[4], w[6], false, false);
        uint2v p3 = __builtin_amdgcn_permlane32_swap(w[5], w[7], false, false);
        uint4 b0 = make_uint4(p0[0], p1[0], p0[1], p1[1]);
        uint4 b1 = make_uint4(p2[0], p3[0], p2[1], p3[1]);
        acc = __builtin_amdgcn_mfma_f32_32x32x16_bf16(as_bf16x8(vv0), as_bf16x8(b0), acc, 0, 0, 0);
        acc = __builtin_amdgcn_mfma_f32_32x32x16_bf16(as_bf16x8(vv1), as_bf16x8(b1), acc, 0, 0, 0);
    };

    const int nfull = n & ~31;
    int k = kw * 32;
    if (k < nfull) {
        uint4 ka0 = ldk0(k), ka1 = ldk1(k), va0 = ldv0(k), va1 = ldv1(k);
        for (; k + 128 < nfull; k += 128) {
            uint4 kb0 = ldk0(k + 128), kb1 = ldk1(k + 128);
            uint4 vb0 = ldv0(k + 128), vb1 = ldv1(k + 128);
            compute(ka0, ka1, va0, va1, k, false);
            ka0 = kb0; ka1 = kb1; va0 = vb0; va1 = vb1;
        }
        compute(ka0, ka1, va0, va1, k, false);
    }
    if ((n & 31) && (((nfull >> 5) & 3) == kw)) {
        uint4 ka0 = ldk0(nfull), ka1 = ldk1(nfull);
        uint4 va0 = ldv0(nfull), va1 = ldv1(nfull);
        compute(ka0, ka1, va0, va1, nfull, true);
    }

    float la = la0 + la1;

    // ---- merge the four key-quarter partials (one LDS round, 3 writers) ----
    if (kw > 0) {
        float* r0 = red + (((size_t)h * 3 + (kw - 1)) * 64 + lane) * 17;
        #pragma unroll
        for (int r = 0; r < 16; ++r) r0[r] = acc[r];
        r0[16] = la;
    }
    __syncthreads();
    float wgt = 0.f;
    if (kw == 0) {
        #pragma unroll
        for (int c = 0; c < 3; ++c) {
            const float* r0 = red + (((size_t)h * 3 + c) * 64 + lane) * 17;
            #pragma unroll
            for (int r = 0; r < 16; ++r) acc[r] += r0[r];
            la += r0[16];
        }
        const float lf = la + __shfl_xor(la, 32);
        wgt = (lf > 0.f) ? (1.0f / lf) : 0.f;     // compacted queries have mask==1
    }
    __syncthreads();                              // red dead; reuse as hd

    // ---- stage normalized O-tile (32 q x 128 d) in LDS as bf16 ----
    if (kw == 0) {
        unsigned short* hrow = hd + ql * 136 + h * DK + 4 * hi;
        #pragma unroll
        for (int g = 0; g < 4; ++g) {             // d = 8g + 4hi + (0..3)
            uint2 p = make_uint2(pack_bf2(acc[4*g+0]*wgt, acc[4*g+1]*wgt),
                                 pack_bf2(acc[4*g+2]*wgt, acc[4*g+3]*wgt));
            *reinterpret_cast<uint2*>(hrow + 8*g) = p;
        }
    }
    __syncthreads();

    // ---- output projection: kw==0 waves, j-quarter = head index ----
    if (kw == 0) {
        const int jq = h;
        f32x16 pacc;
        #pragma unroll
        for (int r = 0; r < 16; ++r) pacc[r] = 0.f;
        #pragma unroll
        for (int ks = 0; ks < 8; ++ks) {
            const int k0 = ks * 16 + 8 * hi;
            uint4 bp = *reinterpret_cast<const uint4*>(hd + ql * 136 + k0);
            const float* wcol = Wo + (size_t)k0 * DM + jq * 32 + ql;
            float w[8];
            #pragma unroll
            for (int i = 0; i < 8; ++i) w[i] = wcol[(size_t)i * DM];
            uint4 ap = make_uint4(pack_bf2(w[0], w[1]), pack_bf2(w[2], w[3]),
                                  pack_bf2(w[4], w[5]), pack_bf2(w[6], w[7]));
            pacc = __builtin_amdgcn_mfma_f32_32x32x16_bf16(as_bf16x8(ap), as_bf16x8(bp), pacc, 0, 0, 0);
        }
        const int i = q0 + ql;
        const bool valid = (i < nq);              // mixed-tile tail lanes -> zeros
        const int pos = valid ? qpos1[b * LSEQ + i] : qpos0[b * LSEQ + (i - nq)];
        float* obase = out + (size_t)b * DM * LSEQ + pos;
        #pragma unroll
        for (int r = 0; r < 16; ++r) {
            const int j = jq * 32 + (r & 3) + 8 * (r >> 2) + 4 * hi;
            obase[(size_t)j * LSEQ] = valid ? pacc[r] : 0.f;
        }
    }
}

extern "C" void kernel_launch(void* const* d_in, const int* in_sizes, int n_in,
                              void* d_out, int out_size, void* d_ws, size_t ws_size,
                              hipStream_t stream)
{
    const float* x    = (const float*)d_in[0];
    const float* mask = (const float*)d_in[1];
    const float* Wq   = (const float*)d_in[2];
    const float* Wk   = (const float*)d_in[3];
    const float* Wv   = (const float*)d_in[4];
    const float* Wo   = (const float*)d_in[5];
    float* out = (float*)d_out;

    char* wsb = (char*)d_ws;
    const size_t NBF = (size_t)BATCH * NH * LSEQ * DK;      // 2,097,152 elems
    unsigned short* Qb  = (unsigned short*)wsb;             // 4MB
    unsigned short* Kb  = Qb + NBF;                         // 4MB
    unsigned short* V4  = Kb + NBF;                         // 4MB frag-layout V
    int* cnt   = (int*)(wsb + 24ull * 1024 * 1024);         // 32B
    int* qpos1 = (int*)(wsb + 24ull * 1024 * 1024 + 4096);  // 64KB (active queries)
    int* qpos0 = qpos1 + (size_t)BATCH * LSEQ;              // 64KB (zeroed queries)

    qkv_mfma_kernel<<<dim3(BATCH, 3, LSEQ / 64), dim3(256), 0, stream>>>(
        x, Wq, Wk, Wv, mask, Qb, Kb, V4, cnt, qpos1, qpos0);
    attnproj_kernel<<<dim3(BATCH * LSEQ / 32), dim3(1024), 0, stream>>>(
        Qb, Kb, V4, cnt, qpos1, qpos0, Wo, out);
}

// Round 20
// 42.362 us; speedup vs baseline: 2.9830x; 1.1095x over previous
//
#include <hip/hip_runtime.h>
#include <hip/hip_bf16.h>
#include <math.h>

#define BATCH 8
#define LSEQ 2048
#define DM 128
#define NH 4
#define DK 32

constexpr float SCALE = 0.17677669529663687f;   // 1/sqrt(32)
constexpr float LOG2E = 1.4426950408889634f;
constexpr float SL = SCALE * LOG2E;             // folded into Q at qkv store

typedef __attribute__((ext_vector_type(8))) __bf16 bf16x8;
typedef __attribute__((ext_vector_type(16))) float f32x16;
typedef __attribute__((ext_vector_type(2))) unsigned uint2v;

__device__ __forceinline__ bf16x8 as_bf16x8(uint4 u) {
    union { uint4 a; bf16x8 b; } c; c.a = u; return c.b;
}
__device__ __forceinline__ unsigned pack_bf2(float lo, float hi) {
    __hip_bfloat162 h = __float22bfloat162_rn(make_float2(lo, hi));
    union { __hip_bfloat162 a; unsigned b; } c; c.a = h; return c.b;
}
__device__ __forceinline__ unsigned short bf16u(float f) {
    union { __hip_bfloat16 h; unsigned short u; } c; c.h = __float2bfloat16(f); return c.u;
}

// ---------- kernel 1: QKV projection via MFMA, fused mask-scan, LDS-staged W ----------
__global__ __launch_bounds__(256) void qkv_mfma_kernel(const float* __restrict__ x,
    const float* __restrict__ Wq, const float* __restrict__ Wk, const float* __restrict__ Wv,
    const float* __restrict__ mask,
    unsigned short* __restrict__ Qb, unsigned short* __restrict__ Kb,
    unsigned short* __restrict__ V4, int* __restrict__ cnt,
    int* __restrict__ qpos1, int* __restrict__ qpos0)
{
    const int b = blockIdx.x;                 // 8
    const int which = blockIdx.y;             // 0=Q 1=K 2=V
    const int lt = blockIdx.z;                // 32 tiles of 64 l
    const int tid = threadIdx.x;
    const int wv = tid >> 6;                  // 4 waves
    const int lane = tid & 63;
    const int ql = lane & 31;
    const int hi = lane >> 5;
    const int l = lt * 64 + (wv & 1) * 32 + ql;   // this lane's output row
    const int hbase = (wv >> 1) * 2;              // head pair

    __shared__ unsigned short wl[4][16][32][8];   // 32KB: [h][d/8][dk][d%8]
    __shared__ int slotbuf[64];                   // zeros_before(l) for this tile
    __shared__ int wsumI[4];

    const float* W = (which == 0 ? Wq : (which == 1 ? Wk : Wv));

    // ---- one-time W stage: 16384 floats, coalesced float4, frag-order bf16 ----
    #pragma unroll
    for (int it = 0; it < 16; ++it) {
        const int flat = (it * 256 + tid) * 4;    // float index into W[which]
        float4 v = *reinterpret_cast<const float4*>(W + flat);
        const int dk0 = flat & 31;
        const int d   = (flat >> 5) & 127;
        const int h   = flat >> 12;
        wl[h][d >> 3][dk0 + 0][d & 7] = bf16u(v.x);
        wl[h][d >> 3][dk0 + 1][d & 7] = bf16u(v.y);
        wl[h][d >> 3][dk0 + 2][d & 7] = bf16u(v.z);
        wl[h][d >> 3][dk0 + 3][d & 7] = bf16u(v.w);
    }

    // ---- fused scan of zeros-prefix (all blocks) ----
    {
        const int nchunk = (lt + 1) * 8;          // 8-elem chunks cover [0, (lt+1)*64)
        int c = 0;
        if (tid < nchunk) {
            const float* mb = mask + (size_t)b * LSEQ + tid * 8;
            #pragma unroll
            for (int i = 0; i < 8; ++i) c += (mb[i] == 0.0f) ? 1 : 0;
        }
        int inc = c;                               // wave-inclusive scan (64 lanes)
        #pragma unroll
        for (int off = 1; off < 64; off <<= 1) {
            int v = __shfl_up(inc, off);
            if (lane >= off) inc += v;
        }
        if (lane == 63) wsumI[wv] = inc;
        __syncthreads();
        int wpre = 0;
        #pragma unroll
        for (int wN = 0; wN < 4; ++wN) if (wN < wv) wpre += wsumI[wN];
        const int excl = wpre + inc - c;           // exclusive prefix of chunk tid
        if (tid >= lt * 8 && tid < lt * 8 + 8) {   // chunks covering this block's 64 l's
            const float* mb = mask + (size_t)b * LSEQ + tid * 8;
            int run = excl;
            #pragma unroll
            for (int i = 0; i < 8; ++i) {
                slotbuf[(tid - lt * 8) * 8 + i] = run;
                run += (mb[i] == 0.0f) ? 1 : 0;
            }
        }
        if (which == 1 && lt == 31 && tid == 255) cnt[b] = wpre + inc;  // total zeros
    }
    __syncthreads();                               // covers W stage + scan

    // ---- position maps (which==1 blocks only; one write per l) ----
    if (which == 1 && tid < 64) {
        const int l64 = lt * 64 + tid;
        const int s = slotbuf[tid];                // zeros before l64
        if (mask[(size_t)b * LSEQ + l64] == 0.0f) qpos0[b * LSEQ + s] = l64;        // zero-output query
        else                                      qpos1[b * LSEQ + (l64 - s)] = l64; // active query
    }

    const float* xcol = x + (size_t)b * DM * LSEQ + l;   // x[b][d][l]

    f32x16 acc0, acc1;
    #pragma unroll
    for (int r = 0; r < 16; ++r) { acc0[r] = 0.f; acc1[r] = 0.f; }

    #pragma unroll
    for (int d0 = 0; d0 < DM; d0 += 16) {
        const int dblk = (d0 >> 3) + hi;
        float xv[8];
        #pragma unroll
        for (int i = 0; i < 8; ++i) xv[i] = xcol[(size_t)(d0 + 8 * hi + i) * LSEQ];
        uint4 xp = make_uint4(pack_bf2(xv[0], xv[1]), pack_bf2(xv[2], xv[3]),
                              pack_bf2(xv[4], xv[5]), pack_bf2(xv[6], xv[7]));
        const bf16x8 xf = as_bf16x8(xp);
        uint4 wp0 = *reinterpret_cast<const uint4*>(&wl[hbase + 0][dblk][ql][0]);
        uint4 wp1 = *reinterpret_cast<const uint4*>(&wl[hbase + 1][dblk][ql][0]);
        acc0 = __builtin_amdgcn_mfma_f32_32x32x16_bf16(as_bf16x8(wp0), xf, acc0, 0, 0, 0);
        acc1 = __builtin_amdgcn_mfma_f32_32x32x16_bf16(as_bf16x8(wp1), xf, acc1, 0, 0, 0);
    }

    // Q compacts by mask==1 (active queries); K/V compact by mask==0 (live keys)
    const float mv = mask[(size_t)b * LSEQ + l];
    const int zb = slotbuf[(wv & 1) * 32 + ql];    // zeros before l
    bool store;
    int slot;
    if (which == 0) { store = (mv != 0.0f); slot = l - zb; }
    else            { store = (mv == 0.0f); slot = zb; }
    if (store) {
        if (which < 2) {
            const float fold = (which == 0) ? SL : 1.0f;
            unsigned short* base0 = (which == 0 ? Qb : Kb);
            #pragma unroll
            for (int hh = 0; hh < 2; ++hh) {
                const f32x16& A = hh ? acc1 : acc0;
                const int bh = b * NH + hbase + hh;
                unsigned short* rowp = base0 + ((size_t)bh * LSEQ + slot) * DK;
                unsigned dw[8];
                #pragma unroll
                for (int j = 0; j < 8; ++j) dw[j] = pack_bf2(A[2*j] * fold, A[2*j+1] * fold);
                *reinterpret_cast<uint2*>(rowp + 4*hi)      = make_uint2(dw[0], dw[1]);
                *reinterpret_cast<uint2*>(rowp + 8 + 4*hi)  = make_uint2(dw[2], dw[3]);
                *reinterpret_cast<uint2*>(rowp + 16 + 4*hi) = make_uint2(dw[4], dw[5]);
                *reinterpret_cast<uint2*>(rowp + 24 + 4*hi) = make_uint2(dw[6], dw[7]);
            }
        } else {
            const int sbase = (slot >> 5) * 1024 + ((slot >> 4) & 1) * 512
                            + ((slot >> 3) & 1) * 256 + (slot & 7) + hi * 32;
            #pragma unroll
            for (int hh = 0; hh < 2; ++hh) {
                const f32x16& A = hh ? acc1 : acc0;
                const int bh = b * NH + hbase + hh;
                unsigned short* vb = V4 + (size_t)bh * (LSEQ * DK) + sbase;
                #pragma unroll
                for (int r = 0; r < 16; ++r)
                    vb[8 * (r & 3) + 64 * (r >> 2)] = bf16u(A[r]);
            }
        }
    }
}

// ---------- kernel 2: fused MFMA flash attention + output projection ----------
// R17 structure (512 thr, 8 waves = 4 heads x 2 key-halves) + depth-2 register
// prefetch (3 named buffer sets, static indexing) + s_setprio around MFMA.
__global__ __launch_bounds__(512, 4) void attnproj_kernel(
    const unsigned short* __restrict__ Qb, const unsigned short* __restrict__ Kb,
    const unsigned short* __restrict__ V4,
    const int* __restrict__ cnt, const int* __restrict__ qpos1,
    const int* __restrict__ qpos0, const float* __restrict__ Wo,
    float* __restrict__ out)
{
    const int b = blockIdx.x & 7;                 // XCD-pinned batch
    const int q0 = (blockIdx.x >> 3) * 32;
    const int tid = threadIdx.x;
    const int wid = tid >> 6;                     // 8 waves
    const int h = wid >> 1;                       // head
    const int kw = wid & 1;                       // key-half owner
    const int lane = tid & 63;
    const int ql = lane & 31;
    const int hi = lane >> 5;
    const int bh = b * NH + h;
    const int n = cnt[b];                         // live keys (mask==0)
    const int nq = LSEQ - n;                      // active queries (mask==1)

    if (q0 >= nq) {                               // pure zero-output block
        if (wid < 4) {
            const int jq = wid;
            const int pos = qpos0[b * LSEQ + (q0 + ql - nq)];
            float* obase = out + (size_t)b * DM * LSEQ + pos;
            #pragma unroll
            for (int r = 0; r < 16; ++r) {
                const int j = jq * 32 + (r & 3) + 8 * (r >> 2) + 4 * hi;
                obase[(size_t)j * LSEQ] = 0.f;
            }
        }
        return;
    }

    __shared__ __align__(16) char smem[17408];
    float* red = reinterpret_cast<float*>(smem);                  // [4][64][17]
    unsigned short* hd = reinterpret_cast<unsigned short*>(smem); // [32][136]

    const uint4* Qp = reinterpret_cast<const uint4*>(Qb + ((size_t)bh * LSEQ + q0 + ql) * DK);
    const bf16x8 qf0 = as_bf16x8(Qp[hi]);         // compacted Q (pre-scaled)
    const bf16x8 qf1 = as_bf16x8(Qp[2 + hi]);

    const unsigned short* Kbase = Kb + (size_t)bh * LSEQ * DK;
    const unsigned short* Vb4   = V4 + (size_t)bh * LSEQ * DK;

    f32x16 acc;
    #pragma unroll
    for (int r = 0; r < 16; ++r) acc[r] = 0.f;
    f32x16 zero;
    #pragma unroll
    for (int r = 0; r < 16; ++r) zero[r] = 0.f;
    float la0 = 0.f, la1 = 0.f;

    auto ldk0 = [&](int k) { return reinterpret_cast<const uint4*>(Kbase + (size_t)(k + ql) * DK)[hi]; };
    auto ldk1 = [&](int k) { return reinterpret_cast<const uint4*>(Kbase + (size_t)(k + ql) * DK)[2 + hi]; };
    auto ldv0 = [&](int k) { return reinterpret_cast<const uint4*>(Vb4 + (size_t)(k >> 5) * 1024)[lane]; };
    auto ldv1 = [&](int k) { return reinterpret_cast<const uint4*>(Vb4 + (size_t)(k >> 5) * 1024)[64 + lane]; };

    auto compute = [&](uint4 kv0, uint4 kv1, uint4 vv0, uint4 vv1, int k0, bool pred) {
        __builtin_amdgcn_s_setprio(1);
        f32x16 s = __builtin_amdgcn_mfma_f32_32x32x16_bf16(as_bf16x8(kv0), qf0, zero, 0, 0, 0);
        s = __builtin_amdgcn_mfma_f32_32x32x16_bf16(as_bf16x8(kv1), qf1, s, 0, 0, 0);
        __builtin_amdgcn_s_setprio(0);
        unsigned w[8];
        #pragma unroll
        for (int j = 0; j < 8; ++j) {
            float e0 = exp2f(s[2*j]);             // key = k0+(r&3)+8*(r>>2)+4*hi
            float e1 = exp2f(s[2*j+1]);
            if (pred) {
                const int r0 = 2*j, r1 = 2*j + 1;
                if (k0 + (r0 & 3) + 8*(r0 >> 2) + 4*hi >= n) e0 = 0.f;
                if (k0 + (r1 & 3) + 8*(r1 >> 2) + 4*hi >= n) e1 = 0.f;
            }
            la0 += e0;
            la1 += e1;
            w[j] = pack_bf2(e0, e1);
        }
        uint2v p0 = __builtin_amdgcn_permlane32_swap(w[0], w[2], false, false);
        uint2v p1 = __builtin_amdgcn_permlane32_swap(w[1], w[3], false, false);
        uint2v p2 = __builtin_amdgcn_permlane32_swap(w[4], w[6], false, false);
        uint2v p3 = __builtin_amdgcn_permlane32_swap(w[5], w[7], false, false);
        uint4 b0 = make_uint4(p0[0], p1[0], p0[1], p1[1]);
        uint4 b1 = make_uint4(p2[0], p3[0], p2[1], p3[1]);
        __builtin_amdgcn_s_setprio(1);
        acc = __builtin_amdgcn_mfma_f32_32x32x16_bf16(as_bf16x8(vv0), as_bf16x8(b0), acc, 0, 0, 0);
        acc = __builtin_amdgcn_mfma_f32_32x32x16_bf16(as_bf16x8(vv1), as_bf16x8(b1), acc, 0, 0, 0);
        __builtin_amdgcn_s_setprio(0);
    };

    // ---- depth-2 software pipeline over tiles (stride 64 within key-half) ----
    const int nfull = n & ~31;
    int k = kw * 32;
    int m = (nfull > k) ? ((nfull - k + 63) >> 6) : 0;   // tiles at k, k+64, ...
    if (m >= 2) {
        uint4 A0 = ldk0(k),      A1 = ldk1(k),      A2 = ldv0(k),      A3 = ldv1(k);
        uint4 B0 = ldk0(k + 64), B1 = ldk1(k + 64), B2 = ldv0(k + 64), B3 = ldv1(k + 64);
        while (m > 2) {
            uint4 C0 = ldk0(k + 128), C1 = ldk1(k + 128), C2 = ldv0(k + 128), C3 = ldv1(k + 128);
            compute(A0, A1, A2, A3, k, false);
            A0 = B0; A1 = B1; A2 = B2; A3 = B3;
            B0 = C0; B1 = C1; B2 = C2; B3 = C3;
            k += 64; --m;
        }
        compute(A0, A1, A2, A3, k, false);
        compute(B0, B1, B2, B3, k + 64, false);
    } else if (m == 1) {
        uint4 A0 = ldk0(k), A1 = ldk1(k), A2 = ldv0(k), A3 = ldv1(k);
        compute(A0, A1, A2, A3, k, false);
    }
    if ((n & 31) && (((nfull >> 5) & 1) == kw)) {
        uint4 A0 = ldk0(nfull), A1 = ldk1(nfull), A2 = ldv0(nfull), A3 = ldv1(nfull);
        compute(A0, A1, A2, A3, nfull, true);
    }

    float la = la0 + la1;

    // ---- merge the two key-half partials (one LDS round) ----
    if (kw == 1) {
        float* r0 = red + ((size_t)h * 64 + lane) * 17;
        #pragma unroll
        for (int r = 0; r < 16; ++r) r0[r] = acc[r];
        r0[16] = la;
    }
    __syncthreads();
    float wgt = 0.f;
    if (kw == 0) {
        const float* r0 = red + ((size_t)h * 64 + lane) * 17;
        #pragma unroll
        for (int r = 0; r < 16; ++r) acc[r] += r0[r];
        la += r0[16];
        const float lf = la + __shfl_xor(la, 32);
        wgt = (lf > 0.f) ? (1.0f / lf) : 0.f;     // compacted queries have mask==1
    }
    __syncthreads();                              // red dead; reuse as hd

    // ---- stage normalized O-tile (32 q x 128 d) in LDS as bf16 ----
    if (kw == 0) {
        unsigned short* hrow = hd + ql * 136 + h * DK + 4 * hi;
        #pragma unroll
        for (int g = 0; g < 4; ++g) {             // d = 8g + 4hi + (0..3)
            uint2 p = make_uint2(pack_bf2(acc[4*g+0]*wgt, acc[4*g+1]*wgt),
                                 pack_bf2(acc[4*g+2]*wgt, acc[4*g+3]*wgt));
            *reinterpret_cast<uint2*>(hrow + 8*g) = p;
        }
    }
    __syncthreads();

    // ---- output projection: waves 0-3, one j-quarter each; scattered cols ----
    if (wid < 4) {
        const int jq = wid;
        f32x16 pacc;
        #pragma unroll
        for (int r = 0; r < 16; ++r) pacc[r] = 0.f;
        #pragma unroll
        for (int ks = 0; ks < 8; ++ks) {
            const int k0 = ks * 16 + 8 * hi;
            uint4 bp = *reinterpret_cast<const uint4*>(hd + ql * 136 + k0);
            const float* wcol = Wo + (size_t)k0 * DM + jq * 32 + ql;
            float w[8];
            #pragma unroll
            for (int i = 0; i < 8; ++i) w[i] = wcol[(size_t)i * DM];
            uint4 ap = make_uint4(pack_bf2(w[0], w[1]), pack_bf2(w[2], w[3]),
                                  pack_bf2(w[4], w[5]), pack_bf2(w[6], w[7]));
            pacc = __builtin_amdgcn_mfma_f32_32x32x16_bf16(as_bf16x8(ap), as_bf16x8(bp), pacc, 0, 0, 0);
        }
        const int i = q0 + ql;
        const bool valid = (i < nq);              // mixed-tile tail lanes -> zeros
        const int pos = valid ? qpos1[b * LSEQ + i] : qpos0[b * LSEQ + (i - nq)];
        float* obase = out + (size_t)b * DM * LSEQ + pos;
        #pragma unroll
        for (int r = 0; r < 16; ++r) {
            const int j = jq * 32 + (r & 3) + 8 * (r >> 2) + 4 * hi;
            obase[(size_t)j * LSEQ] = valid ? pacc[r] : 0.f;
        }
    }
}

extern "C" void kernel_launch(void* const* d_in, const int* in_sizes, int n_in,
                              void* d_out, int out_size, void* d_ws, size_t ws_size,
                              hipStream_t stream)
{
    const float* x    = (const float*)d_in[0];
    const float* mask = (const float*)d_in[1];
    const float* Wq   = (const float*)d_in[2];
    const float* Wk   = (const float*)d_in[3];
    const float* Wv   = (const float*)d_in[4];
    const float* Wo   = (const float*)d_in[5];
    float* out = (float*)d_out;

    char* wsb = (char*)d_ws;
    const size_t NBF = (size_t)BATCH * NH * LSEQ * DK;      // 2,097,152 elems
    unsigned short* Qb  = (unsigned short*)wsb;             // 4MB
    unsigned short* Kb  = Qb + NBF;                         // 4MB
    unsigned short* V4  = Kb + NBF;                         // 4MB frag-layout V
    int* cnt   = (int*)(wsb + 24ull * 1024 * 1024);         // 32B
    int* qpos1 = (int*)(wsb + 24ull * 1024 * 1024 + 4096);  // 64KB (active queries)
    int* qpos0 = qpos1 + (size_t)BATCH * LSEQ;              // 64KB (zeroed queries)

    qkv_mfma_kernel<<<dim3(BATCH, 3, LSEQ / 64), dim3(256), 0, stream>>>(
        x, Wq, Wk, Wv, mask, Qb, Kb, V4, cnt, qpos1, qpos0);
    attnproj_kernel<<<dim3(BATCH * LSEQ / 32), dim3(512), 0, stream>>>(
        Qb, Kb, V4, cnt, qpos1, qpos0, Wo, out);
}

// Round 21
// 35.283 us; speedup vs baseline: 3.5816x; 1.2007x over previous
//
#include <hip/hip_runtime.h>
#include <hip/hip_bf16.h>
#include <math.h>

#define BATCH 8
#define LSEQ 2048
#define DM 128
#define NH 4
#define DK 32

constexpr float SCALE = 0.17677669529663687f;   // 1/sqrt(32)
constexpr float LOG2E = 1.4426950408889634f;
constexpr float SL = SCALE * LOG2E;             // folded into Q at qkv store

typedef __attribute__((ext_vector_type(8))) __bf16 bf16x8;
typedef __attribute__((ext_vector_type(16))) float f32x16;
typedef __attribute__((ext_vector_type(2))) unsigned uint2v;

__device__ __forceinline__ bf16x8 as_bf16x8(uint4 u) {
    union { uint4 a; bf16x8 b; } c; c.a = u; return c.b;
}
__device__ __forceinline__ unsigned pack_bf2(float lo, float hi) {
    __hip_bfloat162 h = __float22bfloat162_rn(make_float2(lo, hi));
    union { __hip_bfloat162 a; unsigned b; } c; c.a = h; return c.b;
}
__device__ __forceinline__ unsigned short bf16u(float f) {
    union { __hip_bfloat16 h; unsigned short u; } c; c.h = __float2bfloat16(f); return c.u;
}

// ---------- kernel 1: QKV projection via MFMA, fused mask-scan, LDS-staged W ----------
__global__ __launch_bounds__(256) void qkv_mfma_kernel(const float* __restrict__ x,
    const float* __restrict__ Wq, const float* __restrict__ Wk, const float* __restrict__ Wv,
    const float* __restrict__ mask,
    unsigned short* __restrict__ Qb, unsigned short* __restrict__ Kb,
    unsigned short* __restrict__ V4, int* __restrict__ cnt,
    int* __restrict__ qpos1, int* __restrict__ qpos0)
{
    const int b = blockIdx.x;                 // 8
    const int which = blockIdx.y;             // 0=Q 1=K 2=V
    const int lt = blockIdx.z;                // 32 tiles of 64 l
    const int tid = threadIdx.x;
    const int wv = tid >> 6;                  // 4 waves
    const int lane = tid & 63;
    const int ql = lane & 31;
    const int hi = lane >> 5;
    const int l = lt * 64 + (wv & 1) * 32 + ql;   // this lane's output row
    const int hbase = (wv >> 1) * 2;              // head pair

    __shared__ unsigned short wl[4][16][32][8];   // 32KB: [h][d/8][dk][d%8]
    __shared__ int slotbuf[64];                   // zeros_before(l) for this tile
    __shared__ int wsumI[4];

    const float* W = (which == 0 ? Wq : (which == 1 ? Wk : Wv));

    // ---- one-time W stage: 16384 floats, coalesced float4, frag-order bf16 ----
    #pragma unroll
    for (int it = 0; it < 16; ++it) {
        const int flat = (it * 256 + tid) * 4;    // float index into W[which]
        float4 v = *reinterpret_cast<const float4*>(W + flat);
        const int dk0 = flat & 31;
        const int d   = (flat >> 5) & 127;
        const int h   = flat >> 12;
        wl[h][d >> 3][dk0 + 0][d & 7] = bf16u(v.x);
        wl[h][d >> 3][dk0 + 1][d & 7] = bf16u(v.y);
        wl[h][d >> 3][dk0 + 2][d & 7] = bf16u(v.z);
        wl[h][d >> 3][dk0 + 3][d & 7] = bf16u(v.w);
    }

    // ---- fused scan of zeros-prefix (all blocks) ----
    {
        const int nchunk = (lt + 1) * 8;          // 8-elem chunks cover [0, (lt+1)*64)
        int c = 0;
        if (tid < nchunk) {
            const float* mb = mask + (size_t)b * LSEQ + tid * 8;
            #pragma unroll
            for (int i = 0; i < 8; ++i) c += (mb[i] == 0.0f) ? 1 : 0;
        }
        int inc = c;                               // wave-inclusive scan (64 lanes)
        #pragma unroll
        for (int off = 1; off < 64; off <<= 1) {
            int v = __shfl_up(inc, off);
            if (lane >= off) inc += v;
        }
        if (lane == 63) wsumI[wv] = inc;
        __syncthreads();
        int wpre = 0;
        #pragma unroll
        for (int wN = 0; wN < 4; ++wN) if (wN < wv) wpre += wsumI[wN];
        const int excl = wpre + inc - c;           // exclusive prefix of chunk tid
        if (tid >= lt * 8 && tid < lt * 8 + 8) {   // chunks covering this block's 64 l's
            const float* mb = mask + (size_t)b * LSEQ + tid * 8;
            int run = excl;
            #pragma unroll
            for (int i = 0; i < 8; ++i) {
                slotbuf[(tid - lt * 8) * 8 + i] = run;
                run += (mb[i] == 0.0f) ? 1 : 0;
            }
        }
        if (which == 1 && lt == 31 && tid == 255) cnt[b] = wpre + inc;  // total zeros
    }
    __syncthreads();                               // covers W stage + scan

    // ---- position maps (which==1 blocks only; one write per l) ----
    if (which == 1 && tid < 64) {
        const int l64 = lt * 64 + tid;
        const int s = slotbuf[tid];                // zeros before l64
        if (mask[(size_t)b * LSEQ + l64] == 0.0f) qpos0[b * LSEQ + s] = l64;        // zero-output query
        else                                      qpos1[b * LSEQ + (l64 - s)] = l64; // active query
    }

    const float* xcol = x + (size_t)b * DM * LSEQ + l;   // x[b][d][l]

    f32x16 acc0, acc1;
    #pragma unroll
    for (int r = 0; r < 16; ++r) { acc0[r] = 0.f; acc1[r] = 0.f; }

    #pragma unroll
    for (int d0 = 0; d0 < DM; d0 += 16) {
        const int dblk = (d0 >> 3) + hi;
        float xv[8];
        #pragma unroll
        for (int i = 0; i < 8; ++i) xv[i] = xcol[(size_t)(d0 + 8 * hi + i) * LSEQ];
        uint4 xp = make_uint4(pack_bf2(xv[0], xv[1]), pack_bf2(xv[2], xv[3]),
                              pack_bf2(xv[4], xv[5]), pack_bf2(xv[6], xv[7]));
        const bf16x8 xf = as_bf16x8(xp);
        uint4 wp0 = *reinterpret_cast<const uint4*>(&wl[hbase + 0][dblk][ql][0]);
        uint4 wp1 = *reinterpret_cast<const uint4*>(&wl[hbase + 1][dblk][ql][0]);
        acc0 = __builtin_amdgcn_mfma_f32_32x32x16_bf16(as_bf16x8(wp0), xf, acc0, 0, 0, 0);
        acc1 = __builtin_amdgcn_mfma_f32_32x32x16_bf16(as_bf16x8(wp1), xf, acc1, 0, 0, 0);
    }

    // Q compacts by mask==1 (active queries); K/V compact by mask==0 (live keys)
    const float mv = mask[(size_t)b * LSEQ + l];
    const int zb = slotbuf[(wv & 1) * 32 + ql];    // zeros before l
    bool store;
    int slot;
    if (which == 0) { store = (mv != 0.0f); slot = l - zb; }
    else            { store = (mv == 0.0f); slot = zb; }
    if (store) {
        if (which < 2) {
            const float fold = (which == 0) ? SL : 1.0f;
            unsigned short* base0 = (which == 0 ? Qb : Kb);
            #pragma unroll
            for (int hh = 0; hh < 2; ++hh) {
                const f32x16& A = hh ? acc1 : acc0;
                const int bh = b * NH + hbase + hh;
                unsigned short* rowp = base0 + ((size_t)bh * LSEQ + slot) * DK;
                unsigned dw[8];
                #pragma unroll
                for (int j = 0; j < 8; ++j) dw[j] = pack_bf2(A[2*j] * fold, A[2*j+1] * fold);
                *reinterpret_cast<uint2*>(rowp + 4*hi)      = make_uint2(dw[0], dw[1]);
                *reinterpret_cast<uint2*>(rowp + 8 + 4*hi)  = make_uint2(dw[2], dw[3]);
                *reinterpret_cast<uint2*>(rowp + 16 + 4*hi) = make_uint2(dw[4], dw[5]);
                *reinterpret_cast<uint2*>(rowp + 24 + 4*hi) = make_uint2(dw[6], dw[7]);
            }
        } else {
            const int sbase = (slot >> 5) * 1024 + ((slot >> 4) & 1) * 512
                            + ((slot >> 3) & 1) * 256 + (slot & 7) + hi * 32;
            #pragma unroll
            for (int hh = 0; hh < 2; ++hh) {
                const f32x16& A = hh ? acc1 : acc0;
                const int bh = b * NH + hbase + hh;
                unsigned short* vb = V4 + (size_t)bh * (LSEQ * DK) + sbase;
                #pragma unroll
                for (int r = 0; r < 16; ++r)
                    vb[8 * (r & 3) + 64 * (r >> 2)] = bf16u(A[r]);
            }
        }
    }
}

// ---------- kernel 2: fused MFMA flash attention + output projection ----------
// R20 structure; exp2f -> __builtin_amdgcn_exp2f (raw v_exp_f32; scores bounded,
// OCML's range/denormal fixup VALU ops are pure overhead here).
__global__ __launch_bounds__(512, 4) void attnproj_kernel(
    const unsigned short* __restrict__ Qb, const unsigned short* __restrict__ Kb,
    const unsigned short* __restrict__ V4,
    const int* __restrict__ cnt, const int* __restrict__ qpos1,
    const int* __restrict__ qpos0, const float* __restrict__ Wo,
    float* __restrict__ out)
{
    const int b = blockIdx.x & 7;                 // XCD-pinned batch
    const int q0 = (blockIdx.x >> 3) * 32;
    const int tid = threadIdx.x;
    const int wid = tid >> 6;                     // 8 waves
    const int h = wid >> 1;                       // head
    const int kw = wid & 1;                       // key-half owner
    const int lane = tid & 63;
    const int ql = lane & 31;
    const int hi = lane >> 5;
    const int bh = b * NH + h;
    const int n = cnt[b];                         // live keys (mask==0)
    const int nq = LSEQ - n;                      // active queries (mask==1)

    if (q0 >= nq) {                               // pure zero-output block
        if (wid < 4) {
            const int jq = wid;
            const int pos = qpos0[b * LSEQ + (q0 + ql - nq)];
            float* obase = out + (size_t)b * DM * LSEQ + pos;
            #pragma unroll
            for (int r = 0; r < 16; ++r) {
                const int j = jq * 32 + (r & 3) + 8 * (r >> 2) + 4 * hi;
                obase[(size_t)j * LSEQ] = 0.f;
            }
        }
        return;
    }

    __shared__ __align__(16) char smem[17408];
    float* red = reinterpret_cast<float*>(smem);                  // [4][64][17]
    unsigned short* hd = reinterpret_cast<unsigned short*>(smem); // [32][136]

    const uint4* Qp = reinterpret_cast<const uint4*>(Qb + ((size_t)bh * LSEQ + q0 + ql) * DK);
    const bf16x8 qf0 = as_bf16x8(Qp[hi]);         // compacted Q (pre-scaled)
    const bf16x8 qf1 = as_bf16x8(Qp[2 + hi]);

    const unsigned short* Kbase = Kb + (size_t)bh * LSEQ * DK;
    const unsigned short* Vb4   = V4 + (size_t)bh * LSEQ * DK;

    f32x16 acc;
    #pragma unroll
    for (int r = 0; r < 16; ++r) acc[r] = 0.f;
    f32x16 zero;
    #pragma unroll
    for (int r = 0; r < 16; ++r) zero[r] = 0.f;
    float la0 = 0.f, la1 = 0.f;

    auto ldk0 = [&](int k) { return reinterpret_cast<const uint4*>(Kbase + (size_t)(k + ql) * DK)[hi]; };
    auto ldk1 = [&](int k) { return reinterpret_cast<const uint4*>(Kbase + (size_t)(k + ql) * DK)[2 + hi]; };
    auto ldv0 = [&](int k) { return reinterpret_cast<const uint4*>(Vb4 + (size_t)(k >> 5) * 1024)[lane]; };
    auto ldv1 = [&](int k) { return reinterpret_cast<const uint4*>(Vb4 + (size_t)(k >> 5) * 1024)[64 + lane]; };

    auto compute = [&](uint4 kv0, uint4 kv1, uint4 vv0, uint4 vv1, int k0, bool pred) {
        __builtin_amdgcn_s_setprio(1);
        f32x16 s = __builtin_amdgcn_mfma_f32_32x32x16_bf16(as_bf16x8(kv0), qf0, zero, 0, 0, 0);
        s = __builtin_amdgcn_mfma_f32_32x32x16_bf16(as_bf16x8(kv1), qf1, s, 0, 0, 0);
        __builtin_amdgcn_s_setprio(0);
        unsigned w[8];
        #pragma unroll
        for (int j = 0; j < 8; ++j) {
            float e0 = __builtin_amdgcn_exp2f(s[2*j]);     // raw v_exp_f32
            float e1 = __builtin_amdgcn_exp2f(s[2*j+1]);
            if (pred) {
                const int r0 = 2*j, r1 = 2*j + 1;
                if (k0 + (r0 & 3) + 8*(r0 >> 2) + 4*hi >= n) e0 = 0.f;
                if (k0 + (r1 & 3) + 8*(r1 >> 2) + 4*hi >= n) e1 = 0.f;
            }
            la0 += e0;
            la1 += e1;
            w[j] = pack_bf2(e0, e1);
        }
        uint2v p0 = __builtin_amdgcn_permlane32_swap(w[0], w[2], false, false);
        uint2v p1 = __builtin_amdgcn_permlane32_swap(w[1], w[3], false, false);
        uint2v p2 = __builtin_amdgcn_permlane32_swap(w[4], w[6], false, false);
        uint2v p3 = __builtin_amdgcn_permlane32_swap(w[5], w[7], false, false);
        uint4 b0 = make_uint4(p0[0], p1[0], p0[1], p1[1]);
        uint4 b1 = make_uint4(p2[0], p3[0], p2[1], p3[1]);
        __builtin_amdgcn_s_setprio(1);
        acc = __builtin_amdgcn_mfma_f32_32x32x16_bf16(as_bf16x8(vv0), as_bf16x8(b0), acc, 0, 0, 0);
        acc = __builtin_amdgcn_mfma_f32_32x32x16_bf16(as_bf16x8(vv1), as_bf16x8(b1), acc, 0, 0, 0);
        __builtin_amdgcn_s_setprio(0);
    };

    // ---- depth-2 software pipeline over tiles (stride 64 within key-half) ----
    const int nfull = n & ~31;
    int k = kw * 32;
    int m = (nfull > k) ? ((nfull - k + 63) >> 6) : 0;   // tiles at k, k+64, ...
    if (m >= 2) {
        uint4 A0 = ldk0(k),      A1 = ldk1(k),      A2 = ldv0(k),      A3 = ldv1(k);
        uint4 B0 = ldk0(k + 64), B1 = ldk1(k + 64), B2 = ldv0(k + 64), B3 = ldv1(k + 64);
        while (m > 2) {
            uint4 C0 = ldk0(k + 128), C1 = ldk1(k + 128), C2 = ldv0(k + 128), C3 = ldv1(k + 128);
            compute(A0, A1, A2, A3, k, false);
            A0 = B0; A1 = B1; A2 = B2; A3 = B3;
            B0 = C0; B1 = C1; B2 = C2; B3 = C3;
            k += 64; --m;
        }
        compute(A0, A1, A2, A3, k, false);
        compute(B0, B1, B2, B3, k + 64, false);
    } else if (m == 1) {
        uint4 A0 = ldk0(k), A1 = ldk1(k), A2 = ldv0(k), A3 = ldv1(k);
        compute(A0, A1, A2, A3, k, false);
    }
    if ((n & 31) && (((nfull >> 5) & 1) == kw)) {
        uint4 A0 = ldk0(nfull), A1 = ldk1(nfull), A2 = ldv0(nfull), A3 = ldv1(nfull);
        compute(A0, A1, A2, A3, nfull, true);
    }

    float la = la0 + la1;

    // ---- merge the two key-half partials (one LDS round) ----
    if (kw == 1) {
        float* r0 = red + ((size_t)h * 64 + lane) * 17;
        #pragma unroll
        for (int r = 0; r < 16; ++r) r0[r] = acc[r];
        r0[16] = la;
    }
    __syncthreads();
    float wgt = 0.f;
    if (kw == 0) {
        const float* r0 = red + ((size_t)h * 64 + lane) * 17;
        #pragma unroll
        for (int r = 0; r < 16; ++r) acc[r] += r0[r];
        la += r0[16];
        const float lf = la + __shfl_xor(la, 32);
        wgt = (lf > 0.f) ? (1.0f / lf) : 0.f;     // compacted queries have mask==1
    }
    __syncthreads();                              // red dead; reuse as hd

    // ---- stage normalized O-tile (32 q x 128 d) in LDS as bf16 ----
    if (kw == 0) {
        unsigned short* hrow = hd + ql * 136 + h * DK + 4 * hi;
        #pragma unroll
        for (int g = 0; g < 4; ++g) {             // d = 8g + 4hi + (0..3)
            uint2 p = make_uint2(pack_bf2(acc[4*g+0]*wgt, acc[4*g+1]*wgt),
                                 pack_bf2(acc[4*g+2]*wgt, acc[4*g+3]*wgt));
            *reinterpret_cast<uint2*>(hrow + 8*g) = p;
        }
    }
    __syncthreads();

    // ---- output projection: waves 0-3, one j-quarter each; scattered cols ----
    if (wid < 4) {
        const int jq = wid;
        f32x16 pacc;
        #pragma unroll
        for (int r = 0; r < 16; ++r) pacc[r] = 0.f;
        #pragma unroll
        for (int ks = 0; ks < 8; ++ks) {
            const int k0 = ks * 16 + 8 * hi;
            uint4 bp = *reinterpret_cast<const uint4*>(hd + ql * 136 + k0);
            const float* wcol = Wo + (size_t)k0 * DM + jq * 32 + ql;
            float w[8];
            #pragma unroll
            for (int i = 0; i < 8; ++i) w[i] = wcol[(size_t)i * DM];
            uint4 ap = make_uint4(pack_bf2(w[0], w[1]), pack_bf2(w[2], w[3]),
                                  pack_bf2(w[4], w[5]), pack_bf2(w[6], w[7]));
            pacc = __builtin_amdgcn_mfma_f32_32x32x16_bf16(as_bf16x8(ap), as_bf16x8(bp), pacc, 0, 0, 0);
        }
        const int i = q0 + ql;
        const bool valid = (i < nq);              // mixed-tile tail lanes -> zeros
        const int pos = valid ? qpos1[b * LSEQ + i] : qpos0[b * LSEQ + (i - nq)];
        float* obase = out + (size_t)b * DM * LSEQ + pos;
        #pragma unroll
        for (int r = 0; r < 16; ++r) {
            const int j = jq * 32 + (r & 3) + 8 * (r >> 2) + 4 * hi;
            obase[(size_t)j * LSEQ] = valid ? pacc[r] : 0.f;
        }
    }
}

extern "C" void kernel_launch(void* const* d_in, const int* in_sizes, int n_in,
                              void* d_out, int out_size, void* d_ws, size_t ws_size,
                              hipStream_t stream)
{
    const float* x    = (const float*)d_in[0];
    const float* mask = (const float*)d_in[1];
    const float* Wq   = (const float*)d_in[2];
    const float* Wk   = (const float*)d_in[3];
    const float* Wv   = (const float*)d_in[4];
    const float* Wo   = (const float*)d_in[5];
    float* out = (float*)d_out;

    char* wsb = (char*)d_ws;
    const size_t NBF = (size_t)BATCH * NH * LSEQ * DK;      // 2,097,152 elems
    unsigned short* Qb  = (unsigned short*)wsb;             // 4MB
    unsigned short* Kb  = Qb + NBF;                         // 4MB
    unsigned short* V4  = Kb + NBF;                         // 4MB frag-layout V
    int* cnt   = (int*)(wsb + 24ull * 1024 * 1024);         // 32B
    int* qpos1 = (int*)(wsb + 24ull * 1024 * 1024 + 4096);  // 64KB (active queries)
    int* qpos0 = qpos1 + (size_t)BATCH * LSEQ;              // 64KB (zeroed queries)

    qkv_mfma_kernel<<<dim3(BATCH, 3, LSEQ / 64), dim3(256), 0, stream>>>(
        x, Wq, Wk, Wv, mask, Qb, Kb, V4, cnt, qpos1, qpos0);
    attnproj_kernel<<<dim3(BATCH * LSEQ / 32), dim3(512), 0, stream>>>(
        Qb, Kb, V4, cnt, qpos1, qpos0, Wo, out);
}

// Round 22
// 35.156 us; speedup vs baseline: 3.5945x; 1.0036x over previous
//
#include <hip/hip_runtime.h>
#include <hip/hip_bf16.h>
#include <math.h>

#define BATCH 8
#define LSEQ 2048
#define DM 128
#define NH 4
#define DK 32

constexpr float SCALE = 0.17677669529663687f;   // 1/sqrt(32)
constexpr float LOG2E = 1.4426950408889634f;
constexpr float SL = SCALE * LOG2E;             // folded into Q at qkv store

typedef __attribute__((ext_vector_type(8))) __bf16 bf16x8;
typedef __attribute__((ext_vector_type(16))) float f32x16;
typedef __attribute__((ext_vector_type(2))) unsigned uint2v;

__device__ __forceinline__ bf16x8 as_bf16x8(uint4 u) {
    union { uint4 a; bf16x8 b; } c; c.a = u; return c.b;
}
__device__ __forceinline__ unsigned pack_bf2(float lo, float hi) {
    __hip_bfloat162 h = __float22bfloat162_rn(make_float2(lo, hi));
    union { __hip_bfloat162 a; unsigned b; } c; c.a = h; return c.b;
}
__device__ __forceinline__ unsigned short bf16u(float f) {
    union { __hip_bfloat16 h; unsigned short u; } c; c.h = __float2bfloat16(f); return c.u;
}

// ---------- kernel 1: QKV projection via MFMA, fused mask-scan, LDS-staged W ----------
// 1-D grid, which in HIGH bits: bid = which*256 + (lt*8 + b). The three blocks
// sharing (b,lt) -- and hence the same x-slice -- are 256 apart => same XCD
// (bid%8), so x is HBM-fetched once per XCD and L2-reused by the other two.
__global__ __launch_bounds__(256) void qkv_mfma_kernel(const float* __restrict__ x,
    const float* __restrict__ Wq, const float* __restrict__ Wk, const float* __restrict__ Wv,
    const float* __restrict__ mask,
    unsigned short* __restrict__ Qb, unsigned short* __restrict__ Kb,
    unsigned short* __restrict__ V4, int* __restrict__ cnt,
    int* __restrict__ qpos1, int* __restrict__ qpos0)
{
    const int bid = blockIdx.x;
    const int which = bid >> 8;               // 0=Q 1=K 2=V
    const int b = bid & 7;                    // 8
    const int lt = (bid & 255) >> 3;          // 32 tiles of 64 l
    const int tid = threadIdx.x;
    const int wv = tid >> 6;                  // 4 waves
    const int lane = tid & 63;
    const int ql = lane & 31;
    const int hi = lane >> 5;
    const int l = lt * 64 + (wv & 1) * 32 + ql;   // this lane's output row
    const int hbase = (wv >> 1) * 2;              // head pair

    __shared__ unsigned short wl[4][16][32][8];   // 32KB: [h][d/8][dk][d%8]
    __shared__ int slotbuf[64];                   // zeros_before(l) for this tile
    __shared__ int wsumI[4];

    const float* W = (which == 0 ? Wq : (which == 1 ? Wk : Wv));

    // ---- one-time W stage: 16384 floats, coalesced float4, frag-order bf16 ----
    #pragma unroll
    for (int it = 0; it < 16; ++it) {
        const int flat = (it * 256 + tid) * 4;    // float index into W[which]
        float4 v = *reinterpret_cast<const float4*>(W + flat);
        const int dk0 = flat & 31;
        const int d   = (flat >> 5) & 127;
        const int h   = flat >> 12;
        wl[h][d >> 3][dk0 + 0][d & 7] = bf16u(v.x);
        wl[h][d >> 3][dk0 + 1][d & 7] = bf16u(v.y);
        wl[h][d >> 3][dk0 + 2][d & 7] = bf16u(v.z);
        wl[h][d >> 3][dk0 + 3][d & 7] = bf16u(v.w);
    }

    // ---- fused scan of zeros-prefix (all blocks) ----
    {
        const int nchunk = (lt + 1) * 8;          // 8-elem chunks cover [0, (lt+1)*64)
        int c = 0;
        if (tid < nchunk) {
            const float* mb = mask + (size_t)b * LSEQ + tid * 8;
            #pragma unroll
            for (int i = 0; i < 8; ++i) c += (mb[i] == 0.0f) ? 1 : 0;
        }
        int inc = c;                               // wave-inclusive scan (64 lanes)
        #pragma unroll
        for (int off = 1; off < 64; off <<= 1) {
            int v = __shfl_up(inc, off);
            if (lane >= off) inc += v;
        }
        if (lane == 63) wsumI[wv] = inc;
        __syncthreads();
        int wpre = 0;
        #pragma unroll
        for (int wN = 0; wN < 4; ++wN) if (wN < wv) wpre += wsumI[wN];
        const int excl = wpre + inc - c;           // exclusive prefix of chunk tid
        if (tid >= lt * 8 && tid < lt * 8 + 8) {   // chunks covering this block's 64 l's
            const float* mb = mask + (size_t)b * LSEQ + tid * 8;
            int run = excl;
            #pragma unroll
            for (int i = 0; i < 8; ++i) {
                slotbuf[(tid - lt * 8) * 8 + i] = run;
                run += (mb[i] == 0.0f) ? 1 : 0;
            }
        }
        if (which == 1 && lt == 31 && tid == 255) cnt[b] = wpre + inc;  // total zeros
    }
    __syncthreads();                               // covers W stage + scan

    // ---- position maps (which==1 blocks only; one write per l) ----
    if (which == 1 && tid < 64) {
        const int l64 = lt * 64 + tid;
        const int s = slotbuf[tid];                // zeros before l64
        if (mask[(size_t)b * LSEQ + l64] == 0.0f) qpos0[b * LSEQ + s] = l64;        // zero-output query
        else                                      qpos1[b * LSEQ + (l64 - s)] = l64; // active query
    }

    const float* xcol = x + (size_t)b * DM * LSEQ + l;   // x[b][d][l]

    f32x16 acc0, acc1;
    #pragma unroll
    for (int r = 0; r < 16; ++r) { acc0[r] = 0.f; acc1[r] = 0.f; }

    #pragma unroll
    for (int d0 = 0; d0 < DM; d0 += 16) {
        const int dblk = (d0 >> 3) + hi;
        float xv[8];
        #pragma unroll
        for (int i = 0; i < 8; ++i) xv[i] = xcol[(size_t)(d0 + 8 * hi + i) * LSEQ];
        uint4 xp = make_uint4(pack_bf2(xv[0], xv[1]), pack_bf2(xv[2], xv[3]),
                              pack_bf2(xv[4], xv[5]), pack_bf2(xv[6], xv[7]));
        const bf16x8 xf = as_bf16x8(xp);
        uint4 wp0 = *reinterpret_cast<const uint4*>(&wl[hbase + 0][dblk][ql][0]);
        uint4 wp1 = *reinterpret_cast<const uint4*>(&wl[hbase + 1][dblk][ql][0]);
        acc0 = __builtin_amdgcn_mfma_f32_32x32x16_bf16(as_bf16x8(wp0), xf, acc0, 0, 0, 0);
        acc1 = __builtin_amdgcn_mfma_f32_32x32x16_bf16(as_bf16x8(wp1), xf, acc1, 0, 0, 0);
    }

    // Q compacts by mask==1 (active queries); K/V compact by mask==0 (live keys)
    const float mv = mask[(size_t)b * LSEQ + l];
    const int zb = slotbuf[(wv & 1) * 32 + ql];    // zeros before l
    bool store;
    int slot;
    if (which == 0) { store = (mv != 0.0f); slot = l - zb; }
    else            { store = (mv == 0.0f); slot = zb; }
    if (store) {
        if (which < 2) {
            const float fold = (which == 0) ? SL : 1.0f;
            unsigned short* base0 = (which == 0 ? Qb : Kb);
            #pragma unroll
            for (int hh = 0; hh < 2; ++hh) {
                const f32x16& A = hh ? acc1 : acc0;
                const int bh = b * NH + hbase + hh;
                unsigned short* rowp = base0 + ((size_t)bh * LSEQ + slot) * DK;
                unsigned dw[8];
                #pragma unroll
                for (int j = 0; j < 8; ++j) dw[j] = pack_bf2(A[2*j] * fold, A[2*j+1] * fold);
                *reinterpret_cast<uint2*>(rowp + 4*hi)      = make_uint2(dw[0], dw[1]);
                *reinterpret_cast<uint2*>(rowp + 8 + 4*hi)  = make_uint2(dw[2], dw[3]);
                *reinterpret_cast<uint2*>(rowp + 16 + 4*hi) = make_uint2(dw[4], dw[5]);
                *reinterpret_cast<uint2*>(rowp + 24 + 4*hi) = make_uint2(dw[6], dw[7]);
            }
        } else {
            const int sbase = (slot >> 5) * 1024 + ((slot >> 4) & 1) * 512
                            + ((slot >> 3) & 1) * 256 + (slot & 7) + hi * 32;
            #pragma unroll
            for (int hh = 0; hh < 2; ++hh) {
                const f32x16& A = hh ? acc1 : acc0;
                const int bh = b * NH + hbase + hh;
                unsigned short* vb = V4 + (size_t)bh * (LSEQ * DK) + sbase;
                #pragma unroll
                for (int r = 0; r < 16; ++r)
                    vb[8 * (r & 3) + 64 * (r >> 2)] = bf16u(A[r]);
            }
        }
    }
}

// ---------- kernel 2: fused MFMA flash attention + output projection ----------
__global__ __launch_bounds__(512, 4) void attnproj_kernel(
    const unsigned short* __restrict__ Qb, const unsigned short* __restrict__ Kb,
    const unsigned short* __restrict__ V4,
    const int* __restrict__ cnt, const int* __restrict__ qpos1,
    const int* __restrict__ qpos0, const float* __restrict__ Wo,
    float* __restrict__ out)
{
    const int b = blockIdx.x & 7;                 // XCD-pinned batch
    const int q0 = (blockIdx.x >> 3) * 32;
    const int tid = threadIdx.x;
    const int wid = tid >> 6;                     // 8 waves
    const int h = wid >> 1;                       // head
    const int kw = wid & 1;                       // key-half owner
    const int lane = tid & 63;
    const int ql = lane & 31;
    const int hi = lane >> 5;
    const int bh = b * NH + h;
    const int n = cnt[b];                         // live keys (mask==0)
    const int nq = LSEQ - n;                      // active queries (mask==1)

    if (q0 >= nq) {                               // pure zero-output block
        if (wid < 4) {
            const int jq = wid;
            const int pos = qpos0[b * LSEQ + (q0 + ql - nq)];
            float* obase = out + (size_t)b * DM * LSEQ + pos;
            #pragma unroll
            for (int r = 0; r < 16; ++r) {
                const int j = jq * 32 + (r & 3) + 8 * (r >> 2) + 4 * hi;
                obase[(size_t)j * LSEQ] = 0.f;
            }
        }
        return;
    }

    __shared__ __align__(16) char smem[17408];
    float* red = reinterpret_cast<float*>(smem);                  // [4][64][17]
    unsigned short* hd = reinterpret_cast<unsigned short*>(smem); // [32][136]

    const uint4* Qp = reinterpret_cast<const uint4*>(Qb + ((size_t)bh * LSEQ + q0 + ql) * DK);
    const bf16x8 qf0 = as_bf16x8(Qp[hi]);         // compacted Q (pre-scaled)
    const bf16x8 qf1 = as_bf16x8(Qp[2 + hi]);

    const unsigned short* Kbase = Kb + (size_t)bh * LSEQ * DK;
    const unsigned short* Vb4   = V4 + (size_t)bh * LSEQ * DK;

    f32x16 acc;
    #pragma unroll
    for (int r = 0; r < 16; ++r) acc[r] = 0.f;
    f32x16 zero;
    #pragma unroll
    for (int r = 0; r < 16; ++r) zero[r] = 0.f;
    float la0 = 0.f, la1 = 0.f;

    auto ldk0 = [&](int k) { return reinterpret_cast<const uint4*>(Kbase + (size_t)(k + ql) * DK)[hi]; };
    auto ldk1 = [&](int k) { return reinterpret_cast<const uint4*>(Kbase + (size_t)(k + ql) * DK)[2 + hi]; };
    auto ldv0 = [&](int k) { return reinterpret_cast<const uint4*>(Vb4 + (size_t)(k >> 5) * 1024)[lane]; };
    auto ldv1 = [&](int k) { return reinterpret_cast<const uint4*>(Vb4 + (size_t)(k >> 5) * 1024)[64 + lane]; };

    auto compute = [&](uint4 kv0, uint4 kv1, uint4 vv0, uint4 vv1, int k0, bool pred) {
        __builtin_amdgcn_s_setprio(1);
        f32x16 s = __builtin_amdgcn_mfma_f32_32x32x16_bf16(as_bf16x8(kv0), qf0, zero, 0, 0, 0);
        s = __builtin_amdgcn_mfma_f32_32x32x16_bf16(as_bf16x8(kv1), qf1, s, 0, 0, 0);
        __builtin_amdgcn_s_setprio(0);
        unsigned w[8];
        #pragma unroll
        for (int j = 0; j < 8; ++j) {
            float e0 = __builtin_amdgcn_exp2f(s[2*j]);     // raw v_exp_f32
            float e1 = __builtin_amdgcn_exp2f(s[2*j+1]);
            if (pred) {
                const int r0 = 2*j, r1 = 2*j + 1;
                if (k0 + (r0 & 3) + 8*(r0 >> 2) + 4*hi >= n) e0 = 0.f;
                if (k0 + (r1 & 3) + 8*(r1 >> 2) + 4*hi >= n) e1 = 0.f;
            }
            la0 += e0;
            la1 += e1;
            w[j] = pack_bf2(e0, e1);
        }
        uint2v p0 = __builtin_amdgcn_permlane32_swap(w[0], w[2], false, false);
        uint2v p1 = __builtin_amdgcn_permlane32_swap(w[1], w[3], false, false);
        uint2v p2 = __builtin_amdgcn_permlane32_swap(w[4], w[6], false, false);
        uint2v p3 = __builtin_amdgcn_permlane32_swap(w[5], w[7], false, false);
        uint4 b0 = make_uint4(p0[0], p1[0], p0[1], p1[1]);
        uint4 b1 = make_uint4(p2[0], p3[0], p2[1], p3[1]);
        __builtin_amdgcn_s_setprio(1);
        acc = __builtin_amdgcn_mfma_f32_32x32x16_bf16(as_bf16x8(vv0), as_bf16x8(b0), acc, 0, 0, 0);
        acc = __builtin_amdgcn_mfma_f32_32x32x16_bf16(as_bf16x8(vv1), as_bf16x8(b1), acc, 0, 0, 0);
        __builtin_amdgcn_s_setprio(0);
    };

    // ---- depth-2 software pipeline over tiles (stride 64 within key-half) ----
    const int nfull = n & ~31;
    int k = kw * 32;
    int m = (nfull > k) ? ((nfull - k + 63) >> 6) : 0;   // tiles at k, k+64, ...
    if (m >= 2) {
        uint4 A0 = ldk0(k),      A1 = ldk1(k),      A2 = ldv0(k),      A3 = ldv1(k);
        uint4 B0 = ldk0(k + 64), B1 = ldk1(k + 64), B2 = ldv0(k + 64), B3 = ldv1(k + 64);
        while (m > 2) {
            uint4 C0 = ldk0(k + 128), C1 = ldk1(k + 128), C2 = ldv0(k + 128), C3 = ldv1(k + 128);
            compute(A0, A1, A2, A3, k, false);
            A0 = B0; A1 = B1; A2 = B2; A3 = B3;
            B0 = C0; B1 = C1; B2 = C2; B3 = C3;
            k += 64; --m;
        }
        compute(A0, A1, A2, A3, k, false);
        compute(B0, B1, B2, B3, k + 64, false);
    } else if (m == 1) {
        uint4 A0 = ldk0(k), A1 = ldk1(k), A2 = ldv0(k), A3 = ldv1(k);
        compute(A0, A1, A2, A3, k, false);
    }
    if ((n & 31) && (((nfull >> 5) & 1) == kw)) {
        uint4 A0 = ldk0(nfull), A1 = ldk1(nfull), A2 = ldv0(nfull), A3 = ldv1(nfull);
        compute(A0, A1, A2, A3, nfull, true);
    }

    float la = la0 + la1;

    // ---- merge the two key-half partials (one LDS round) ----
    if (kw == 1) {
        float* r0 = red + ((size_t)h * 64 + lane) * 17;
        #pragma unroll
        for (int r = 0; r < 16; ++r) r0[r] = acc[r];
        r0[16] = la;
    }
    __syncthreads();
    float wgt = 0.f;
    if (kw == 0) {
        const float* r0 = red + ((size_t)h * 64 + lane) * 17;
        #pragma unroll
        for (int r = 0; r < 16; ++r) acc[r] += r0[r];
        la += r0[16];
        const float lf = la + __shfl_xor(la, 32);
        wgt = (lf > 0.f) ? (1.0f / lf) : 0.f;     // compacted queries have mask==1
    }
    __syncthreads();                              // red dead; reuse as hd

    // ---- stage normalized O-tile (32 q x 128 d) in LDS as bf16 ----
    if (kw == 0) {
        unsigned short* hrow = hd + ql * 136 + h * DK + 4 * hi;
        #pragma unroll
        for (int g = 0; g < 4; ++g) {             // d = 8g + 4hi + (0..3)
            uint2 p = make_uint2(pack_bf2(acc[4*g+0]*wgt, acc[4*g+1]*wgt),
                                 pack_bf2(acc[4*g+2]*wgt, acc[4*g+3]*wgt));
            *reinterpret_cast<uint2*>(hrow + 8*g) = p;
        }
    }
    __syncthreads();

    // ---- output projection: waves 0-3, one j-quarter each; scattered cols ----
    if (wid < 4) {
        const int jq = wid;
        f32x16 pacc;
        #pragma unroll
        for (int r = 0; r < 16; ++r) pacc[r] = 0.f;
        #pragma unroll
        for (int ks = 0; ks < 8; ++ks) {
            const int k0 = ks * 16 + 8 * hi;
            uint4 bp = *reinterpret_cast<const uint4*>(hd + ql * 136 + k0);
            const float* wcol = Wo + (size_t)k0 * DM + jq * 32 + ql;
            float w[8];
            #pragma unroll
            for (int i = 0; i < 8; ++i) w[i] = wcol[(size_t)i * DM];
            uint4 ap = make_uint4(pack_bf2(w[0], w[1]), pack_bf2(w[2], w[3]),
                                  pack_bf2(w[4], w[5]), pack_bf2(w[6], w[7]));
            pacc = __builtin_amdgcn_mfma_f32_32x32x16_bf16(as_bf16x8(ap), as_bf16x8(bp), pacc, 0, 0, 0);
        }
        const int i = q0 + ql;
        const bool valid = (i < nq);              // mixed-tile tail lanes -> zeros
        const int pos = valid ? qpos1[b * LSEQ + i] : qpos0[b * LSEQ + (i - nq)];
        float* obase = out + (size_t)b * DM * LSEQ + pos;
        #pragma unroll
        for (int r = 0; r < 16; ++r) {
            const int j = jq * 32 + (r & 3) + 8 * (r >> 2) + 4 * hi;
            obase[(size_t)j * LSEQ] = valid ? pacc[r] : 0.f;
        }
    }
}

extern "C" void kernel_launch(void* const* d_in, const int* in_sizes, int n_in,
                              void* d_out, int out_size, void* d_ws, size_t ws_size,
                              hipStream_t stream)
{
    const float* x    = (const float*)d_in[0];
    const float* mask = (const float*)d_in[1];
    const float* Wq   = (const float*)d_in[2];
    const float* Wk   = (const float*)d_in[3];
    const float* Wv   = (const float*)d_in[4];
    const float* Wo   = (const float*)d_in[5];
    float* out = (float*)d_out;

    char* wsb = (char*)d_ws;
    const size_t NBF = (size_t)BATCH * NH * LSEQ * DK;      // 2,097,152 elems
    unsigned short* Qb  = (unsigned short*)wsb;             // 4MB
    unsigned short* Kb  = Qb + NBF;                         // 4MB
    unsigned short* V4  = Kb + NBF;                         // 4MB frag-layout V
    int* cnt   = (int*)(wsb + 24ull * 1024 * 1024);         // 32B
    int* qpos1 = (int*)(wsb + 24ull * 1024 * 1024 + 4096);  // 64KB (active queries)
    int* qpos0 = qpos1 + (size_t)BATCH * LSEQ;              // 64KB (zeroed queries)

    qkv_mfma_kernel<<<dim3(768), dim3(256), 0, stream>>>(
        x, Wq, Wk, Wv, mask, Qb, Kb, V4, cnt, qpos1, qpos0);
    attnproj_kernel<<<dim3(BATCH * LSEQ / 32), dim3(512), 0, stream>>>(
        Qb, Kb, V4, cnt, qpos1, qpos0, Wo, out);
}